// Round 6
// baseline (2675.726 us; speedup 1.0000x reference)
//
#include <hip/hip_runtime.h>
#include <cstdint>

#define TT  3
#define FIN 4
#define HID 128

typedef unsigned int   u32;
typedef unsigned short u16;
typedef unsigned long long u64;
typedef float f32x4 __attribute__((ext_vector_type(4)));
typedef __bf16 bf16x8 __attribute__((ext_vector_type(8)));

static __device__ __forceinline__ f32x4 mfma_bf16(bf16x8 a, bf16x8 b, f32x4 c) {
  return __builtin_amdgcn_mfma_f32_16x16x32_bf16(a, b, c, 0, 0, 0);
}
static __device__ __forceinline__ float sigf(float v) { return 1.f / (1.f + __expf(-v)); }
static __device__ __forceinline__ float tanhfast(float v) {
  return 2.f / (1.f + __expf(-2.f * v)) - 1.f;
}
static __device__ __forceinline__ float bf_lo(u32 u) { return __uint_as_float(u << 16); }
static __device__ __forceinline__ float bf_hi(u32 u) { return __uint_as_float(u & 0xffff0000u); }
static __device__ __forceinline__ u16 bfbits(float f) {
  return __builtin_bit_cast(unsigned short, (__bf16)f);
}

// fused BN-stats tail: block reduce -> replicated atomics -> ticket last-block affine
static __device__ __forceinline__ void stats_tail(
    float (*red)[4], int* lastf,
    float s1a, float s2a, float s1b, float s2b,
    float* statsbuf, int* ticket,
    const float* gamma, const float* beta, float* aout, float* bout, int N_) {
  int l = threadIdx.x & 63;
  red[threadIdx.x][0] = s1a; red[threadIdx.x][1] = s2a;
  red[threadIdx.x][2] = s1b; red[threadIdx.x][3] = s2b;
  __syncthreads();
  if ((threadIdx.x >> 6) == 0) {
    float a0 = 0, a1 = 0, a2 = 0, a3 = 0;
    #pragma unroll
    for (int h2 = 0; h2 < 4; ++h2) {
      a0 += red[h2*64 + l][0]; a1 += red[h2*64 + l][1];
      a2 += red[h2*64 + l][2]; a3 += red[h2*64 + l][3];
    }
    float* sb = statsbuf + (size_t)(blockIdx.x & 15) * 256;
    atomicAdd(&sb[2*l], a0);       atomicAdd(&sb[HID + 2*l], a1);
    atomicAdd(&sb[2*l + 1], a2);   atomicAdd(&sb[HID + 2*l + 1], a3);
  }
  __syncthreads();
  if (threadIdx.x == 0) {
    __threadfence();
    int tk = __hip_atomic_fetch_add(ticket, 1, __ATOMIC_ACQ_REL, __HIP_MEMORY_SCOPE_AGENT);
    *lastf = (tk == (int)gridDim.x - 1) ? 1 : 0;
  }
  __syncthreads();
  if (*lastf) {
    if (threadIdx.x < HID) {
      int c = threadIdx.x;
      float s1 = 0.f, s2 = 0.f;
      #pragma unroll
      for (int k = 0; k < 16; ++k) {
        s1 += __hip_atomic_load(&statsbuf[k*256 + c],       __ATOMIC_RELAXED, __HIP_MEMORY_SCOPE_AGENT);
        s2 += __hip_atomic_load(&statsbuf[k*256 + HID + c], __ATOMIC_RELAXED, __HIP_MEMORY_SCOPE_AGENT);
      }
      float invn = 1.f / (float)N_;
      float mu = s1 * invn;
      float var = fmaxf(s2 * invn - mu * mu, 0.f);
      float a = gamma[c] * rsqrtf(var + 1e-5f);
      aout[c] = a;
      bout[c] = beta[c] - mu * a;
    }
    __syncthreads();
    for (int i = threadIdx.x; i < 4096; i += 256) statsbuf[i] = 0.f;
    if (threadIdx.x == 0) *ticket = 0;
  }
}

// ---------------- graph preprocessing ----------------

__global__ void k_init(u64* pk, float* statsbuf, int* ticket, int n) {
  int i = blockIdx.x * 256 + threadIdx.x;
  if (i < n) pk[i] = 0ull;
  if (blockIdx.x == 0) {
    for (int k = 0; k < 16; ++k) statsbuf[k * 256 + threadIdx.x] = 0.f;
    if (threadIdx.x == 0) *ticket = 0;
  }
}

// one u64 atomic per edge: hi 22 bits = count, low 42 bits = Q10.32 weight sum.
__global__ void k_deg(const int* __restrict__ dstv, const float* __restrict__ ew,
                      u64* pk, int* __restrict__ epos, int E_) {
  int e = blockIdx.x * 256 + threadIdx.x;
  if (e < E_) {
    int d = dstv[e];
    u64 inc = (1ull << 42) | (u64)(ew[e] * 4294967296.0f);
    u64 old = atomicAdd(&pk[d], inc);
    epos[e] = (int)(old >> 42);
  }
}

__global__ __launch_bounds__(256) void k_scanA(const u64* __restrict__ pk, int* rowptr,
    int* partial, float* dinv, float* selfn, int n) {
  __shared__ int wsum[4];
  int tid = threadIdx.x, lane = tid & 63, wv = tid >> 6;
  int i = blockIdx.x * 256 + tid;
  int v = 0;
  if (i < n) {
    u64 p = pk[i];
    v = (int)(p >> 42);
    float degw = (float)((double)(p & ((1ull << 42) - 1)) * (1.0 / 4294967296.0) + 1.0);
    float r = rsqrtf(degw);
    dinv[i] = r; selfn[i] = r * r;
  }
  int inc = v;
  #pragma unroll
  for (int off = 1; off < 64; off <<= 1) {
    int t2 = __shfl_up(inc, off);
    if (lane >= off) inc += t2;
  }
  if (lane == 63) wsum[wv] = inc;
  __syncthreads();
  if (tid == 0) {
    int s = 0;
    #pragma unroll
    for (int j = 0; j < 4; ++j) { int t3 = wsum[j]; wsum[j] = s; s += t3; }
    partial[blockIdx.x] = s;
  }
  __syncthreads();
  int excl = wsum[wv] + inc - v;
  if (i <= n) rowptr[i] = excl;
}

__global__ __launch_bounds__(256) void k_scanB(int* partial, int nb) {
  __shared__ int wsum[4];
  int tid = threadIdx.x, lane = tid & 63, wv = tid >> 6;
  int v = (tid < nb) ? partial[tid] : 0;
  int inc = v;
  #pragma unroll
  for (int off = 1; off < 64; off <<= 1) {
    int t2 = __shfl_up(inc, off);
    if (lane >= off) inc += t2;
  }
  if (lane == 63) wsum[wv] = inc;
  __syncthreads();
  if (tid == 0) {
    int s = 0;
    #pragma unroll
    for (int j = 0; j < 4; ++j) { int t3 = wsum[j]; wsum[j] = s; s += t3; }
  }
  __syncthreads();
  int excl = wsum[wv] + inc - v;
  if (tid < nb) partial[tid] = excl;
}

__global__ void k_scanC(int* rowptr, const int* __restrict__ partial, int n) {
  int i = blockIdx.x * 256 + threadIdx.x;
  if (i <= n) rowptr[i] += partial[blockIdx.x];
}

__global__ void k_fillcsr(const int* __restrict__ srcv, const int* __restrict__ dstv,
                          const float* __restrict__ ew, const float* __restrict__ dinv,
                          const int* __restrict__ rowptr, const int* __restrict__ epos,
                          int2* __restrict__ csr, int E_) {
  int e = blockIdx.x * 256 + threadIdx.x;
  if (e < E_) {
    int d = dstv[e], s = srcv[e];
    int idx = rowptr[d] + epos[e];
    csr[idx] = make_int2(s, __float_as_int(dinv[s] * ew[e] * dinv[d]));
  }
}

// ---------------- layer-0: aggregate X (12 feats) ----------------

__global__ __launch_bounds__(256) void k_aggX(const float* __restrict__ X,
    const int* __restrict__ rowptr, const int2* __restrict__ csr,
    const float* __restrict__ selfn, float* __restrict__ XA, int N_) {
  int wv = threadIdx.x >> 6, l = threadIdx.x & 63;
  int wid = blockIdx.x * 4 + wv, nw = gridDim.x * 4;
  for (int n = wid; n < N_; n += nw) {
    float acc[12];
    #pragma unroll
    for (int i = 0; i < 12; ++i) acc[i] = 0.f;
    int e0 = rowptr[n], e1 = rowptr[n + 1];
    for (int e = e0 + l; e < e1; e += 64) {
      int2 v2 = csr[e];
      int s = v2.x; float wn = __int_as_float(v2.y);
      #pragma unroll
      for (int t = 0; t < TT; ++t) {
        float4 v = *(const float4*)(X + ((size_t)t * N_ + s) * FIN);
        acc[t*4+0] += wn * v.x; acc[t*4+1] += wn * v.y;
        acc[t*4+2] += wn * v.z; acc[t*4+3] += wn * v.w;
      }
    }
    #pragma unroll
    for (int i = 0; i < 12; ++i)
      for (int off = 32; off; off >>= 1) acc[i] += __shfl_down(acc[i], off);
    if (l == 0) {
      float sn = selfn[n];
      #pragma unroll
      for (int t = 0; t < TT; ++t) {
        float4 v = *(const float4*)(X + ((size_t)t * N_ + n) * FIN);
        XA[(size_t)n*12 + t*4+0] = acc[t*4+0] + sn * v.x;
        XA[(size_t)n*12 + t*4+1] = acc[t*4+1] + sn * v.y;
        XA[(size_t)n*12 + t*4+2] = acc[t*4+2] + sn * v.z;
        XA[(size_t)n*12 + t*4+3] = acc[t*4+3] + sn * v.w;
      }
    }
  }
}

// layer-0 transform + relu + fused BN stats
__global__ __launch_bounds__(256) void k_l0s(const float* __restrict__ XA,
    const float* __restrict__ w1, const float* __restrict__ bc0, u32* __restrict__ out32,
    float* statsbuf, int* ticket, const float* __restrict__ gamma,
    const float* __restrict__ beta, float* aout, float* bout, int t, int N_) {
  __shared__ float red[256][4];
  __shared__ int lastf;
  int l = threadIdx.x & 63, half = threadIdx.x >> 6;
  int cp = 2 * l;
  float w00 = w1[cp],         w01 = w1[cp+1];
  float w10 = w1[HID+cp],     w11 = w1[HID+cp+1];
  float w20 = w1[2*HID+cp],   w21 = w1[2*HID+cp+1];
  float w30 = w1[3*HID+cp],   w31 = w1[3*HID+cp+1];
  float b0 = bc0[cp], b1 = bc0[cp+1];
  float s1a = 0, s2a = 0, s1b = 0, s2b = 0;
  for (int n = blockIdx.x * 4 + half; n < N_; n += gridDim.x * 4) {
    float4 x = *(const float4*)(XA + (size_t)n * 12 + t * 4);
    float v0 = fmaxf(b0 + x.x*w00 + x.y*w10 + x.z*w20 + x.w*w30, 0.f);
    float v1 = fmaxf(b1 + x.x*w01 + x.y*w11 + x.z*w21 + x.w*w31, 0.f);
    s1a += v0; s2a += v0*v0; s1b += v1; s2b += v1*v1;
    out32[(size_t)n * 64 + l] = (u32)bfbits(v0) | ((u32)bfbits(v1) << 16);
  }
  stats_tail(red, &lastf, s1a, s2a, s1b, s2b, statsbuf, ticket, gamma, beta, aout, bout, N_);
}

// ---------------- weight swizzles ----------------
// GCN: frag (kb,cb): col = cb*16+lr, k0 = kb*32+lk*8
// LSTM (gate-interleaved): frag ((kb*4+q)*8+cb): gate=cb>>1, jblk=cb&1,
//   col = gate*128 + q*32 + jblk*16 + lr; k0 = kb*32 + lk*8 (kb 0..7 over K=256)
__global__ void k_swzall(const float* __restrict__ wc, const float* __restrict__ wih,
                         const float* __restrict__ whh,
                         bf16x8* __restrict__ wcsw, bf16x8* __restrict__ wstk) {
  int id = blockIdx.x * 256 + threadIdx.x;
  if (id < 6144) {
    int i = id >> 11, lid = id & 2047;
    int l = lid & 63, frag = lid >> 6;
    int cb = frag & 7, kb = frag >> 3;
    int col = cb * 16 + (l & 15);
    int k0 = kb * 32 + (l >> 4) * 8;
    const float* W = wc + (size_t)i * HID * HID;
    bf16x8 v;
    #pragma unroll
    for (int j = 0; j < 8; ++j) v[j] = (__bf16)W[(size_t)(k0 + j) * HID + col];
    wcsw[i * 2048 + lid] = v;
  } else if (id < 6144 + 32768) {
    int id2 = id - 6144;
    int layer = id2 >> 14, lid = id2 & 16383;
    int l = lid & 63, frag = lid >> 6;      // frag 0..255
    int cb = frag & 7, q = (frag >> 3) & 3, kb = frag >> 5;
    int col = (cb >> 1) * 128 + q * 32 + (cb & 1) * 16 + (l & 15);
    int k0 = kb * 32 + (l >> 4) * 8;
    const float* wi = wih + (size_t)layer * 512 * HID;
    const float* wh = whh + (size_t)layer * 512 * HID;
    bf16x8 v;
    #pragma unroll
    for (int j = 0; j < 8; ++j) {
      int k = k0 + j;
      float val = (k < HID) ? wi[(size_t)col * HID + k] : wh[(size_t)col * HID + (k - HID)];
      v[j] = (__bf16)val;
    }
    wstk[layer * 16384 + lid] = v;
  }
}

// collapsed head: Wc[k] = sum_j lin1_w[k][j]*lin2_w[j]; b = lin1_b@lin2_w + lin2_b
__global__ void k_headprep(const float* __restrict__ l1w, const float* __restrict__ l1b,
                           const float* __restrict__ l2w, const float* __restrict__ l2b,
                           float* __restrict__ hw) {
  int k = threadIdx.x;
  if (k < HID + TT) {
    float s = 0.f;
    for (int j = 0; j < HID; ++j) s += l1w[(size_t)k * HID + j] * l2w[j];
    hw[k] = s;
  } else if (k == HID + TT) {
    float s = l2b[0];
    for (int j = 0; j < HID; ++j) s += l1b[j] * l2w[j];
    hw[HID + TT] = s;
  }
}

// ---------------- MFMA transform: Y = affine(bf16 X) @ W, bf16 out ----------------

__global__ __launch_bounds__(256) void k_trans(const u16* __restrict__ Xin,
    const float* __restrict__ fa, const float* __restrict__ fb,
    const bf16x8* __restrict__ wsw, u16* __restrict__ Y, int N_) {
  int w = threadIdx.x >> 6, l = threadIdx.x & 63;
  int lr = l & 15, lk = l >> 4;
  int rbase = blockIdx.x * 64 + w * 16;
  int arow = rbase + lr;
  bool av = arow < N_;
  f32x4 acc[8];
  #pragma unroll
  for (int cb = 0; cb < 8; ++cb) acc[cb] = (f32x4){0.f, 0.f, 0.f, 0.f};
  #pragma unroll
  for (int kb = 0; kb < 4; ++kb) {
    int ko = kb * 32 + lk * 8;
    bf16x8 af;
    if (av) {
      uint4 u = *(const uint4*)(Xin + (size_t)arow * HID + ko);
      float4 a0 = *(const float4*)(fa + ko), a1 = *(const float4*)(fa + ko + 4);
      float4 b0 = *(const float4*)(fb + ko), b1 = *(const float4*)(fb + ko + 4);
      af[0] = (__bf16)(bf_lo(u.x) * a0.x + b0.x);
      af[1] = (__bf16)(bf_hi(u.x) * a0.y + b0.y);
      af[2] = (__bf16)(bf_lo(u.y) * a0.z + b0.z);
      af[3] = (__bf16)(bf_hi(u.y) * a0.w + b0.w);
      af[4] = (__bf16)(bf_lo(u.z) * a1.x + b1.x);
      af[5] = (__bf16)(bf_hi(u.z) * a1.y + b1.y);
      af[6] = (__bf16)(bf_lo(u.w) * a1.z + b1.z);
      af[7] = (__bf16)(bf_hi(u.w) * a1.w + b1.w);
    } else {
      #pragma unroll
      for (int j = 0; j < 8; ++j) af[j] = (__bf16)0.f;
    }
    #pragma unroll
    for (int cb = 0; cb < 8; ++cb) {
      bf16x8 bf = wsw[(kb * 8 + cb) * 64 + l];
      acc[cb] = mfma_bf16(af, bf, acc[cb]);
    }
  }
  #pragma unroll
  for (int cb = 0; cb < 8; ++cb)
    #pragma unroll
    for (int i2 = 0; i2 < 4; ++i2) {
      int orow = rbase + lk * 4 + i2;
      if (orow < N_) Y[(size_t)orow * HID + cb * 16 + lr] = bfbits(acc[cb][i2]);
    }
}

// ---------------- 128-wide aggregation + bias + relu + fused BN stats ----------------

__global__ __launch_bounds__(256) void k_aggs(const u32* __restrict__ H32,
    const int* __restrict__ rowptr, const int2* __restrict__ csr,
    const float* __restrict__ selfn, const float* __restrict__ bias,
    u32* __restrict__ out32, float* statsbuf, int* ticket,
    const float* __restrict__ gamma, const float* __restrict__ beta,
    float* aout, float* bout, int N_) {
  __shared__ float red[256][4];
  __shared__ int lastf;
  int wv = threadIdx.x >> 6, l = threadIdx.x & 63;
  int wid = blockIdx.x * 4 + wv, nw = gridDim.x * 4;
  float b0 = bias[2 * l], b1 = bias[2 * l + 1];
  float s1a = 0, s2a = 0, s1b = 0, s2b = 0;
  for (int n = wid; n < N_; n += nw) {
    u32 u = H32[(size_t)n * 64 + l];
    float sn = selfn[n];
    float a0 = sn * bf_lo(u);
    float a1 = sn * bf_hi(u);
    int e0 = rowptr[n], e1 = rowptr[n + 1];
    int e = e0;
    for (; e + 7 < e1; e += 8) {
      int2 c0 = csr[e],   c1 = csr[e+1], c2 = csr[e+2], c3 = csr[e+3];
      int2 c4 = csr[e+4], c5 = csr[e+5], c6 = csr[e+6], c7 = csr[e+7];
      u32 x0 = H32[(size_t)c0.x * 64 + l];
      u32 x1 = H32[(size_t)c1.x * 64 + l];
      u32 x2 = H32[(size_t)c2.x * 64 + l];
      u32 x3 = H32[(size_t)c3.x * 64 + l];
      u32 x4 = H32[(size_t)c4.x * 64 + l];
      u32 x5 = H32[(size_t)c5.x * 64 + l];
      u32 x6 = H32[(size_t)c6.x * 64 + l];
      u32 x7 = H32[(size_t)c7.x * 64 + l];
      a0 += __int_as_float(c0.y) * bf_lo(x0) + __int_as_float(c1.y) * bf_lo(x1)
          + __int_as_float(c2.y) * bf_lo(x2) + __int_as_float(c3.y) * bf_lo(x3)
          + __int_as_float(c4.y) * bf_lo(x4) + __int_as_float(c5.y) * bf_lo(x5)
          + __int_as_float(c6.y) * bf_lo(x6) + __int_as_float(c7.y) * bf_lo(x7);
      a1 += __int_as_float(c0.y) * bf_hi(x0) + __int_as_float(c1.y) * bf_hi(x1)
          + __int_as_float(c2.y) * bf_hi(x2) + __int_as_float(c3.y) * bf_hi(x3)
          + __int_as_float(c4.y) * bf_hi(x4) + __int_as_float(c5.y) * bf_hi(x5)
          + __int_as_float(c6.y) * bf_hi(x6) + __int_as_float(c7.y) * bf_hi(x7);
    }
    for (; e < e1; ++e) {
      int2 c0 = csr[e];
      u32 x0 = H32[(size_t)c0.x * 64 + l];
      float w0 = __int_as_float(c0.y);
      a0 += w0 * bf_lo(x0);
      a1 += w0 * bf_hi(x0);
    }
    float v0 = fmaxf(a0 + b0, 0.f), v1 = fmaxf(a1 + b1, 0.f);
    s1a += v0; s2a += v0*v0; s1b += v1; s2b += v1*v1;
    out32[(size_t)n * 64 + l] = (u32)bfbits(v0) | ((u32)bfbits(v1) << 16);
  }
  stats_tail(red, &lastf, s1a, s2a, s1b, s2b, statsbuf, ticket, gamma, beta, aout, bout, N_);
}

// ---------------- fully-fused LSTM: both layers x all timesteps ----------------
// LOW-PRESSURE variant: 32 rows/block, 512 thr = 8 waves = q(4) x hf(2);
// each wave owns ONE 16-row MFMA row-block and one col-quarter.
// Per-thread live state ~90 VGPR -> fits default 128 cap, NO spill.
// Gates in registers; c1/c2 in registers across timesteps; h1/h2 in LDS.

__global__ __launch_bounds__(512) void k_lstm_all(
    const u16* __restrict__ G0, const float* __restrict__ aff3, u32* __restrict__ h2out,
    const bf16x8* __restrict__ w1sw, const bf16x8* __restrict__ w2sw,
    const float* __restrict__ b1, const float* __restrict__ b2, int N_) {
  __shared__ __bf16 h1l[32][136];
  __shared__ __bf16 h2l[32][136];
  int l = threadIdx.x & 63, w8 = threadIdx.x >> 6;
  int q = w8 & 3, hf = w8 >> 2;      // hf in {0,1}
  int lr = l & 15, lk = l >> 4;
  int r0 = blockIdx.x * 32;
  int myrow = r0 + hf * 16 + lr;     // this lane's A-operand row
  bool rv = myrow < N_;
  const size_t strideT = (size_t)N_ * HID;

  float c1r[4][2], c2r[4][2];
  #pragma unroll
  for (int i2 = 0; i2 < 4; ++i2)
    #pragma unroll
    for (int jb = 0; jb < 2; ++jb) { c1r[i2][jb] = 0.f; c2r[i2][jb] = 0.f; }

  float bia1[4][2], bia2[4][2];
  #pragma unroll
  for (int g = 0; g < 4; ++g)
    #pragma unroll
    for (int jb = 0; jb < 2; ++jb) {
      int col = g * 128 + q * 32 + jb * 16 + lr;
      bia1[g][jb] = b1[col];
      bia2[g][jb] = b2[col];
    }

  #pragma unroll 1
  for (int t = 0; t < TT; ++t) {
    const u16* xg = G0 + (size_t)t * strideT;
    const float* aff = aff3 + (size_t)t * 256;
    f32x4 acc[8];

    // ---- layer-1 gates GEMM (acc init = bias) ----
    #pragma unroll
    for (int cb = 0; cb < 8; ++cb) {
      float b = bia1[cb >> 1][cb & 1];
      acc[cb] = (f32x4){b, b, b, b};
    }
    #pragma unroll
    for (int kb = 0; kb < 4; ++kb) {
      int ko = kb * 32 + lk * 8;
      bf16x8 af;
      if (rv) {
        uint4 u = *(const uint4*)(xg + (size_t)myrow * HID + ko);
        float4 a0 = *(const float4*)(aff + ko),       a1 = *(const float4*)(aff + ko + 4);
        float4 b0 = *(const float4*)(aff + HID + ko), b1v = *(const float4*)(aff + HID + ko + 4);
        af[0] = (__bf16)(bf_lo(u.x) * a0.x + b0.x);
        af[1] = (__bf16)(bf_hi(u.x) * a0.y + b0.y);
        af[2] = (__bf16)(bf_lo(u.y) * a0.z + b0.z);
        af[3] = (__bf16)(bf_hi(u.y) * a0.w + b0.w);
        af[4] = (__bf16)(bf_lo(u.z) * a1.x + b1v.x);
        af[5] = (__bf16)(bf_hi(u.z) * a1.y + b1v.y);
        af[6] = (__bf16)(bf_lo(u.w) * a1.z + b1v.z);
        af[7] = (__bf16)(bf_hi(u.w) * a1.w + b1v.w);
      } else {
        #pragma unroll
        for (int j = 0; j < 8; ++j) af[j] = (__bf16)0.f;
      }
      #pragma unroll
      for (int cb = 0; cb < 8; ++cb) {
        bf16x8 bf = w1sw[(size_t)(((kb * 4 + q) * 8 + cb) * 64 + l)];
        acc[cb] = mfma_bf16(af, bf, acc[cb]);
      }
    }
    if (t > 0) {
      #pragma unroll
      for (int kb = 0; kb < 4; ++kb) {
        int ko = kb * 32 + lk * 8;
        bf16x8 af = *(const bf16x8*)&h1l[hf * 16 + lr][ko];
        #pragma unroll
        for (int cb = 0; cb < 8; ++cb) {
          bf16x8 bf = w1sw[(size_t)((((kb + 4) * 4 + q) * 8 + cb) * 64 + l)];
          acc[cb] = mfma_bf16(af, bf, acc[cb]);
        }
      }
    }
    __syncthreads();   // all reads of h1l(prev) done

    // ---- layer-1 cell (pure registers) -> h1l ----
    #pragma unroll
    for (int i2 = 0; i2 < 4; ++i2)
      #pragma unroll
      for (int jb = 0; jb < 2; ++jb) {
        float ig = acc[jb][i2];
        float fg = acc[2 + jb][i2];
        float gg = acc[4 + jb][i2];
        float og = acc[6 + jb][i2];
        float cn = sigf(fg) * c1r[i2][jb] + sigf(ig) * tanhfast(gg);
        float hn = sigf(og) * tanhfast(cn);
        c1r[i2][jb] = cn;
        h1l[hf * 16 + lk * 4 + i2][q * 32 + jb * 16 + lr] = (__bf16)hn;
      }
    __syncthreads();   // h1l(new) visible

    // ---- layer-2 gates GEMM ----
    #pragma unroll
    for (int cb = 0; cb < 8; ++cb) {
      float b = bia2[cb >> 1][cb & 1];
      acc[cb] = (f32x4){b, b, b, b};
    }
    #pragma unroll
    for (int kb = 0; kb < 4; ++kb) {
      int ko = kb * 32 + lk * 8;
      bf16x8 af = *(const bf16x8*)&h1l[hf * 16 + lr][ko];
      #pragma unroll
      for (int cb = 0; cb < 8; ++cb) {
        bf16x8 bf = w2sw[(size_t)(((kb * 4 + q) * 8 + cb) * 64 + l)];
        acc[cb] = mfma_bf16(af, bf, acc[cb]);
      }
    }
    if (t > 0) {
      #pragma unroll
      for (int kb = 0; kb < 4; ++kb) {
        int ko = kb * 32 + lk * 8;
        bf16x8 af = *(const bf16x8*)&h2l[hf * 16 + lr][ko];
        #pragma unroll
        for (int cb = 0; cb < 8; ++cb) {
          bf16x8 bf = w2sw[(size_t)((((kb + 4) * 4 + q) * 8 + cb) * 64 + l)];
          acc[cb] = mfma_bf16(af, bf, acc[cb]);
        }
      }
    }
    __syncthreads();   // all reads of h2l(prev) done

    // ---- layer-2 cell -> h2l ----
    #pragma unroll
    for (int i2 = 0; i2 < 4; ++i2)
      #pragma unroll
      for (int jb = 0; jb < 2; ++jb) {
        float ig = acc[jb][i2];
        float fg = acc[2 + jb][i2];
        float gg = acc[4 + jb][i2];
        float og = acc[6 + jb][i2];
        float cn = sigf(fg) * c2r[i2][jb] + sigf(ig) * tanhfast(gg);
        float hn = sigf(og) * tanhfast(cn);
        c2r[i2][jb] = cn;
        h2l[hf * 16 + lk * 4 + i2][q * 32 + jb * 16 + lr] = (__bf16)hn;
      }
    __syncthreads();   // h2l(new) visible
  }

  // coalesced copy-out of final h2
  for (int idx = threadIdx.x; idx < 32 * 64; idx += 512) {
    int row = idx >> 6, l2 = idx & 63;
    int n = r0 + row;
    if (n < N_) h2out[(size_t)n * 64 + l2] = *(const u32*)&h2l[row][2 * l2];
  }
}

// ---------------- final head: out[n] = relu(h2[n]) . Wc + S . Ws + b ----------------

__global__ __launch_bounds__(256) void k_final2(const u32* __restrict__ H2,
    const float* __restrict__ Xin, const float* __restrict__ hw,
    float* __restrict__ outp, int N_) {
  int wv = threadIdx.x >> 6, l = threadIdx.x & 63;
  int wid = blockIdx.x * 4 + wv, nw = gridDim.x * 4;
  float wc0 = hw[2 * l], wc1 = hw[2 * l + 1];
  float ws0 = hw[HID], ws1 = hw[HID + 1], ws2 = hw[HID + 2], bb = hw[HID + 3];
  for (int n = wid; n < N_; n += nw) {
    u32 u = H2[(size_t)n * 64 + l];
    float p = fmaxf(bf_lo(u), 0.f) * wc0 + fmaxf(bf_hi(u), 0.f) * wc1;
    #pragma unroll
    for (int off = 32; off; off >>= 1) p += __shfl_down(p, off);
    if (l == 0) {
      p += Xin[(size_t)n * FIN] * ws0
         + Xin[((size_t)N_ + n) * FIN] * ws1
         + Xin[((size_t)2 * N_ + n) * FIN] * ws2;
      outp[n] = p + bb;
    }
  }
}

// ---------------- host ----------------

extern "C" void kernel_launch(void* const* d_in, const int* in_sizes, int n_in,
                              void* d_out, int out_size, void* d_ws, size_t ws_size,
                              hipStream_t stream) {
  const float* X   = (const float*)d_in[0];
  const int*   ei  = (const int*)  d_in[1];
  const float* ew  = (const float*)d_in[2];
  const float* w1  = (const float*)d_in[3];
  const float* wc  = (const float*)d_in[4];
  const float* bc  = (const float*)d_in[5];
  const float* gam = (const float*)d_in[6];
  const float* bet = (const float*)d_in[7];
  const float* wih = (const float*)d_in[8];
  const float* whh = (const float*)d_in[9];
  const float* lb  = (const float*)d_in[10];
  const float* l1w = (const float*)d_in[11];
  const float* l1b = (const float*)d_in[12];
  const float* l2w = (const float*)d_in[13];
  const float* l2b = (const float*)d_in[14];
  float* outp = (float*)d_out;
  (void)n_in; (void)out_size; (void)ws_size;

  const int N = in_sizes[0] / (TT * FIN);
  const int E = in_sizes[1] / 2;
  const int* srcv = ei;
  const int* dstv = ei + E;

  char* base = (char*)d_ws;
  size_t off = 0;
  auto alloc = [&](size_t b) -> void* {
    void* p = base + off;
    off += (b + 255) & ~(size_t)255;
    return p;
  };

  u64*   pk     = (u64*)  alloc((size_t)N * 8);
  int*   epos   = (int*)  alloc((size_t)E * 4);
  int*   rowptr = (int*)  alloc(((size_t)N + 1) * 4);
  int*   partial= (int*)  alloc(1024);
  float* dinv   = (float*)alloc((size_t)N * 4);
  float* selfn  = (float*)alloc((size_t)N * 4);
  int2*  csr    = (int2*) alloc((size_t)E * 8);
  float* XA     = (float*)alloc((size_t)N * 12 * 4);
  u32*   Ga     = (u32*)  alloc((size_t)N * 64 * 4);
  u32*   Gb     = (u32*)  alloc((size_t)N * 64 * 4);   // doubles as h2 final
  u32*   Gfin   = (u32*)  alloc((size_t)3 * N * 64 * 4);
  u32*   Htb    = (u32*)  alloc((size_t)N * 64 * 4);
  float* statsb = (float*)alloc(16 * 256 * 4);
  int*   ticket = (int*)  alloc(256);
  float* aff    = (float*)alloc(256 * 4);
  float* aff3   = (float*)alloc((size_t)3 * 256 * 4);
  float* hw     = (float*)alloc(136 * 4);
  bf16x8* wcsw  = (bf16x8*)alloc((size_t)3 * 2048 * 16);
  bf16x8* wstk  = (bf16x8*)alloc((size_t)2 * 16384 * 16);

  int gN = (N + 255) / 256, gE = (E + 255) / 256;
  int nb = (N + 255) / 256;

  k_init<<<gN, 256, 0, stream>>>(pk, statsb, ticket, N);
  k_deg<<<gE, 256, 0, stream>>>(dstv, ew, pk, epos, E);
  k_scanA<<<nb, 256, 0, stream>>>(pk, rowptr, partial, dinv, selfn, N);
  k_scanB<<<1, 256, 0, stream>>>(partial, nb);
  k_scanC<<<nb, 256, 0, stream>>>(rowptr, partial, N);
  k_fillcsr<<<gE, 256, 0, stream>>>(srcv, dstv, ew, dinv, rowptr, epos, csr, E);
  k_aggX<<<1024, 256, 0, stream>>>(X, rowptr, csr, selfn, XA, N);
  k_swzall<<<152, 256, 0, stream>>>(wc, wih, whh, wcsw, wstk);
  k_headprep<<<1, 256, 0, stream>>>(l1w, l1b, l2w, l2b, hw);

  for (int t = 0; t < TT; ++t) {
    u32* Gt = Gfin + (size_t)t * N * 64;
    float* afft = aff3 + (size_t)t * 256;
    k_l0s<<<512, 256, 0, stream>>>(XA, w1, bc, Ga, statsb, ticket, gam, bet,
                                   aff, aff + HID, t, N);
    k_trans<<<(N + 63) / 64, 256, 0, stream>>>((const u16*)Ga, aff, aff + HID, wcsw,
                                               (u16*)Htb, N);
    k_aggs<<<2048, 256, 0, stream>>>(Htb, rowptr, csr, selfn, bc + HID, Gb,
                                     statsb, ticket, gam + HID, bet + HID,
                                     aff, aff + HID, N);
    k_trans<<<(N + 63) / 64, 256, 0, stream>>>((const u16*)Gb, aff, aff + HID, wcsw + 2048,
                                               (u16*)Htb, N);
    k_aggs<<<2048, 256, 0, stream>>>(Htb, rowptr, csr, selfn, bc + 2 * HID, Ga,
                                     statsb, ticket, gam + 2 * HID, bet + 2 * HID,
                                     aff, aff + HID, N);
    k_trans<<<(N + 63) / 64, 256, 0, stream>>>((const u16*)Ga, aff, aff + HID, wcsw + 4096,
                                               (u16*)Htb, N);
    k_aggs<<<2048, 256, 0, stream>>>(Htb, rowptr, csr, selfn, bc + 3 * HID, Gt,
                                     statsb, ticket, gam + 3 * HID, bet + 3 * HID,
                                     afft, afft + HID, N);
  }

  k_lstm_all<<<(N + 31) / 32, 512, 0, stream>>>(
      (const u16*)Gfin, aff3, Gb, wstk, wstk + 16384, lb, lb + 512, N);

  k_final2<<<512, 256, 0, stream>>>((const u32*)Gb, X, hw, outp, N);
}

// Round 7
// 2201.076 us; speedup vs baseline: 1.2156x; 1.2156x over previous
//
#include <hip/hip_runtime.h>
#include <cstdint>

#define TT  3
#define FIN 4
#define HID 128

typedef unsigned int   u32;
typedef unsigned short u16;
typedef unsigned long long u64;
typedef float f32x4 __attribute__((ext_vector_type(4)));
typedef __bf16 bf16x8 __attribute__((ext_vector_type(8)));

static __device__ __forceinline__ f32x4 mfma_bf16(bf16x8 a, bf16x8 b, f32x4 c) {
  return __builtin_amdgcn_mfma_f32_16x16x32_bf16(a, b, c, 0, 0, 0);
}
static __device__ __forceinline__ float sigf(float v) { return 1.f / (1.f + __expf(-v)); }
static __device__ __forceinline__ float tanhfast(float v) {
  return 2.f / (1.f + __expf(-2.f * v)) - 1.f;
}
static __device__ __forceinline__ float bf_lo(u32 u) { return __uint_as_float(u << 16); }
static __device__ __forceinline__ float bf_hi(u32 u) { return __uint_as_float(u & 0xffff0000u); }
static __device__ __forceinline__ u16 bfbits(float f) {
  return __builtin_bit_cast(unsigned short, (__bf16)f);
}

// fused BN-stats tail: block reduce -> replicated atomics -> ticket last-block affine
static __device__ __forceinline__ void stats_tail(
    float (*red)[4], int* lastf,
    float s1a, float s2a, float s1b, float s2b,
    float* statsbuf, int* ticket,
    const float* gamma, const float* beta, float* aout, float* bout, int N_) {
  int l = threadIdx.x & 63;
  red[threadIdx.x][0] = s1a; red[threadIdx.x][1] = s2a;
  red[threadIdx.x][2] = s1b; red[threadIdx.x][3] = s2b;
  __syncthreads();
  if ((threadIdx.x >> 6) == 0) {
    float a0 = 0, a1 = 0, a2 = 0, a3 = 0;
    #pragma unroll
    for (int h2 = 0; h2 < 4; ++h2) {
      a0 += red[h2*64 + l][0]; a1 += red[h2*64 + l][1];
      a2 += red[h2*64 + l][2]; a3 += red[h2*64 + l][3];
    }
    float* sb = statsbuf + (size_t)(blockIdx.x & 15) * 256;
    atomicAdd(&sb[2*l], a0);       atomicAdd(&sb[HID + 2*l], a1);
    atomicAdd(&sb[2*l + 1], a2);   atomicAdd(&sb[HID + 2*l + 1], a3);
  }
  __syncthreads();
  if (threadIdx.x == 0) {
    __threadfence();
    int tk = __hip_atomic_fetch_add(ticket, 1, __ATOMIC_ACQ_REL, __HIP_MEMORY_SCOPE_AGENT);
    *lastf = (tk == (int)gridDim.x - 1) ? 1 : 0;
  }
  __syncthreads();
  if (*lastf) {
    if (threadIdx.x < HID) {
      int c = threadIdx.x;
      float s1 = 0.f, s2 = 0.f;
      #pragma unroll
      for (int k = 0; k < 16; ++k) {
        s1 += __hip_atomic_load(&statsbuf[k*256 + c],       __ATOMIC_RELAXED, __HIP_MEMORY_SCOPE_AGENT);
        s2 += __hip_atomic_load(&statsbuf[k*256 + HID + c], __ATOMIC_RELAXED, __HIP_MEMORY_SCOPE_AGENT);
      }
      float invn = 1.f / (float)N_;
      float mu = s1 * invn;
      float var = fmaxf(s2 * invn - mu * mu, 0.f);
      float a = gamma[c] * rsqrtf(var + 1e-5f);
      aout[c] = a;
      bout[c] = beta[c] - mu * a;
    }
    __syncthreads();
    for (int i = threadIdx.x; i < 4096; i += 256) statsbuf[i] = 0.f;
    if (threadIdx.x == 0) *ticket = 0;
  }
}

// ---------------- graph preprocessing ----------------

__global__ void k_init(u64* pk, float* statsbuf, int* ticket, int n) {
  int i = blockIdx.x * 256 + threadIdx.x;
  if (i < n) pk[i] = 0ull;
  if (blockIdx.x == 0) {
    for (int k = 0; k < 16; ++k) statsbuf[k * 256 + threadIdx.x] = 0.f;
    if (threadIdx.x == 0) *ticket = 0;
  }
}

// one u64 atomic per edge: hi 22 bits = count, low 42 bits = Q10.32 weight sum.
__global__ void k_deg(const int* __restrict__ dstv, const float* __restrict__ ew,
                      u64* pk, int* __restrict__ epos, int E_) {
  int e = blockIdx.x * 256 + threadIdx.x;
  if (e < E_) {
    int d = dstv[e];
    u64 inc = (1ull << 42) | (u64)(ew[e] * 4294967296.0f);
    u64 old = atomicAdd(&pk[d], inc);
    epos[e] = (int)(old >> 42);
  }
}

__global__ __launch_bounds__(256) void k_scanA(const u64* __restrict__ pk, int* rowptr,
    int* partial, float* dinv, float* selfn, int n) {
  __shared__ int wsum[4];
  int tid = threadIdx.x, lane = tid & 63, wv = tid >> 6;
  int i = blockIdx.x * 256 + tid;
  int v = 0;
  if (i < n) {
    u64 p = pk[i];
    v = (int)(p >> 42);
    float degw = (float)((double)(p & ((1ull << 42) - 1)) * (1.0 / 4294967296.0) + 1.0);
    float r = rsqrtf(degw);
    dinv[i] = r; selfn[i] = r * r;
  }
  int inc = v;
  #pragma unroll
  for (int off = 1; off < 64; off <<= 1) {
    int t2 = __shfl_up(inc, off);
    if (lane >= off) inc += t2;
  }
  if (lane == 63) wsum[wv] = inc;
  __syncthreads();
  if (tid == 0) {
    int s = 0;
    #pragma unroll
    for (int j = 0; j < 4; ++j) { int t3 = wsum[j]; wsum[j] = s; s += t3; }
    partial[blockIdx.x] = s;
  }
  __syncthreads();
  int excl = wsum[wv] + inc - v;
  if (i <= n) rowptr[i] = excl;
}

__global__ __launch_bounds__(256) void k_scanB(int* partial, int nb) {
  __shared__ int wsum[4];
  int tid = threadIdx.x, lane = tid & 63, wv = tid >> 6;
  int v = (tid < nb) ? partial[tid] : 0;
  int inc = v;
  #pragma unroll
  for (int off = 1; off < 64; off <<= 1) {
    int t2 = __shfl_up(inc, off);
    if (lane >= off) inc += t2;
  }
  if (lane == 63) wsum[wv] = inc;
  __syncthreads();
  if (tid == 0) {
    int s = 0;
    #pragma unroll
    for (int j = 0; j < 4; ++j) { int t3 = wsum[j]; wsum[j] = s; s += t3; }
  }
  __syncthreads();
  int excl = wsum[wv] + inc - v;
  if (tid < nb) partial[tid] = excl;
}

__global__ void k_scanC(int* rowptr, const int* __restrict__ partial, int n) {
  int i = blockIdx.x * 256 + threadIdx.x;
  if (i <= n) rowptr[i] += partial[blockIdx.x];
}

__global__ void k_fillcsr(const int* __restrict__ srcv, const int* __restrict__ dstv,
                          const float* __restrict__ ew, const float* __restrict__ dinv,
                          const int* __restrict__ rowptr, const int* __restrict__ epos,
                          int2* __restrict__ csr, int E_) {
  int e = blockIdx.x * 256 + threadIdx.x;
  if (e < E_) {
    int d = dstv[e], s = srcv[e];
    int idx = rowptr[d] + epos[e];
    csr[idx] = make_int2(s, __float_as_int(dinv[s] * ew[e] * dinv[d]));
  }
}

// ---------------- layer-0: aggregate X (12 feats) ----------------

__global__ __launch_bounds__(256) void k_aggX(const float* __restrict__ X,
    const int* __restrict__ rowptr, const int2* __restrict__ csr,
    const float* __restrict__ selfn, float* __restrict__ XA, int N_) {
  int wv = threadIdx.x >> 6, l = threadIdx.x & 63;
  int wid = blockIdx.x * 4 + wv, nw = gridDim.x * 4;
  for (int n = wid; n < N_; n += nw) {
    float acc[12];
    #pragma unroll
    for (int i = 0; i < 12; ++i) acc[i] = 0.f;
    int e0 = rowptr[n], e1 = rowptr[n + 1];
    for (int e = e0 + l; e < e1; e += 64) {
      int2 v2 = csr[e];
      int s = v2.x; float wn = __int_as_float(v2.y);
      #pragma unroll
      for (int t = 0; t < TT; ++t) {
        float4 v = *(const float4*)(X + ((size_t)t * N_ + s) * FIN);
        acc[t*4+0] += wn * v.x; acc[t*4+1] += wn * v.y;
        acc[t*4+2] += wn * v.z; acc[t*4+3] += wn * v.w;
      }
    }
    #pragma unroll
    for (int i = 0; i < 12; ++i)
      for (int off = 32; off; off >>= 1) acc[i] += __shfl_down(acc[i], off);
    if (l == 0) {
      float sn = selfn[n];
      #pragma unroll
      for (int t = 0; t < TT; ++t) {
        float4 v = *(const float4*)(X + ((size_t)t * N_ + n) * FIN);
        XA[(size_t)n*12 + t*4+0] = acc[t*4+0] + sn * v.x;
        XA[(size_t)n*12 + t*4+1] = acc[t*4+1] + sn * v.y;
        XA[(size_t)n*12 + t*4+2] = acc[t*4+2] + sn * v.z;
        XA[(size_t)n*12 + t*4+3] = acc[t*4+3] + sn * v.w;
      }
    }
  }
}

// layer-0 transform + relu + fused BN stats
__global__ __launch_bounds__(256) void k_l0s(const float* __restrict__ XA,
    const float* __restrict__ w1, const float* __restrict__ bc0, u32* __restrict__ out32,
    float* statsbuf, int* ticket, const float* __restrict__ gamma,
    const float* __restrict__ beta, float* aout, float* bout, int t, int N_) {
  __shared__ float red[256][4];
  __shared__ int lastf;
  int l = threadIdx.x & 63, half = threadIdx.x >> 6;
  int cp = 2 * l;
  float w00 = w1[cp],         w01 = w1[cp+1];
  float w10 = w1[HID+cp],     w11 = w1[HID+cp+1];
  float w20 = w1[2*HID+cp],   w21 = w1[2*HID+cp+1];
  float w30 = w1[3*HID+cp],   w31 = w1[3*HID+cp+1];
  float b0 = bc0[cp], b1 = bc0[cp+1];
  float s1a = 0, s2a = 0, s1b = 0, s2b = 0;
  for (int n = blockIdx.x * 4 + half; n < N_; n += gridDim.x * 4) {
    float4 x = *(const float4*)(XA + (size_t)n * 12 + t * 4);
    float v0 = fmaxf(b0 + x.x*w00 + x.y*w10 + x.z*w20 + x.w*w30, 0.f);
    float v1 = fmaxf(b1 + x.x*w01 + x.y*w11 + x.z*w21 + x.w*w31, 0.f);
    s1a += v0; s2a += v0*v0; s1b += v1; s2b += v1*v1;
    out32[(size_t)n * 64 + l] = (u32)bfbits(v0) | ((u32)bfbits(v1) << 16);
  }
  stats_tail(red, &lastf, s1a, s2a, s1b, s2b, statsbuf, ticket, gamma, beta, aout, bout, N_);
}

// ---------------- weight swizzles ----------------
// GCN: frag (kb,cb): col = cb*16+lr, k0 = kb*32+lk*8
// LSTM (gate-interleaved): frag ((kb*4+q)*8+cb): gate=cb>>1, jblk=cb&1,
//   col = gate*128 + q*32 + jblk*16 + lr; k0 = kb*32 + lk*8 (kb 0..7 over K=256)
__global__ void k_swzall(const float* __restrict__ wc, const float* __restrict__ wih,
                         const float* __restrict__ whh,
                         bf16x8* __restrict__ wcsw, bf16x8* __restrict__ wstk) {
  int id = blockIdx.x * 256 + threadIdx.x;
  if (id < 6144) {
    int i = id >> 11, lid = id & 2047;
    int l = lid & 63, frag = lid >> 6;
    int cb = frag & 7, kb = frag >> 3;
    int col = cb * 16 + (l & 15);
    int k0 = kb * 32 + (l >> 4) * 8;
    const float* W = wc + (size_t)i * HID * HID;
    bf16x8 v;
    #pragma unroll
    for (int j = 0; j < 8; ++j) v[j] = (__bf16)W[(size_t)(k0 + j) * HID + col];
    wcsw[i * 2048 + lid] = v;
  } else if (id < 6144 + 32768) {
    int id2 = id - 6144;
    int layer = id2 >> 14, lid = id2 & 16383;
    int l = lid & 63, frag = lid >> 6;      // frag 0..255
    int cb = frag & 7, q = (frag >> 3) & 3, kb = frag >> 5;
    int col = (cb >> 1) * 128 + q * 32 + (cb & 1) * 16 + (l & 15);
    int k0 = kb * 32 + (l >> 4) * 8;
    const float* wi = wih + (size_t)layer * 512 * HID;
    const float* wh = whh + (size_t)layer * 512 * HID;
    bf16x8 v;
    #pragma unroll
    for (int j = 0; j < 8; ++j) {
      int k = k0 + j;
      float val = (k < HID) ? wi[(size_t)col * HID + k] : wh[(size_t)col * HID + (k - HID)];
      v[j] = (__bf16)val;
    }
    wstk[layer * 16384 + lid] = v;
  }
}

// collapsed head: Wc[k] = sum_j lin1_w[k][j]*lin2_w[j]; b = lin1_b@lin2_w + lin2_b
__global__ void k_headprep(const float* __restrict__ l1w, const float* __restrict__ l1b,
                           const float* __restrict__ l2w, const float* __restrict__ l2b,
                           float* __restrict__ hw) {
  int k = threadIdx.x;
  if (k < HID + TT) {
    float s = 0.f;
    for (int j = 0; j < HID; ++j) s += l1w[(size_t)k * HID + j] * l2w[j];
    hw[k] = s;
  } else if (k == HID + TT) {
    float s = l2b[0];
    for (int j = 0; j < HID; ++j) s += l1b[j] * l2w[j];
    hw[HID + TT] = s;
  }
}

// ---------------- MFMA transform: Y = affine(bf16 X) @ W, bf16 out ----------------

__global__ __launch_bounds__(256) void k_trans(const u16* __restrict__ Xin,
    const float* __restrict__ fa, const float* __restrict__ fb,
    const bf16x8* __restrict__ wsw, u16* __restrict__ Y, int N_) {
  int w = threadIdx.x >> 6, l = threadIdx.x & 63;
  int lr = l & 15, lk = l >> 4;
  int rbase = blockIdx.x * 64 + w * 16;
  int arow = rbase + lr;
  bool av = arow < N_;
  f32x4 acc[8];
  #pragma unroll
  for (int cb = 0; cb < 8; ++cb) acc[cb] = (f32x4){0.f, 0.f, 0.f, 0.f};
  #pragma unroll
  for (int kb = 0; kb < 4; ++kb) {
    int ko = kb * 32 + lk * 8;
    bf16x8 af;
    if (av) {
      uint4 u = *(const uint4*)(Xin + (size_t)arow * HID + ko);
      float4 a0 = *(const float4*)(fa + ko), a1 = *(const float4*)(fa + ko + 4);
      float4 b0 = *(const float4*)(fb + ko), b1 = *(const float4*)(fb + ko + 4);
      af[0] = (__bf16)(bf_lo(u.x) * a0.x + b0.x);
      af[1] = (__bf16)(bf_hi(u.x) * a0.y + b0.y);
      af[2] = (__bf16)(bf_lo(u.y) * a0.z + b0.z);
      af[3] = (__bf16)(bf_hi(u.y) * a0.w + b0.w);
      af[4] = (__bf16)(bf_lo(u.z) * a1.x + b1.x);
      af[5] = (__bf16)(bf_hi(u.z) * a1.y + b1.y);
      af[6] = (__bf16)(bf_lo(u.w) * a1.z + b1.z);
      af[7] = (__bf16)(bf_hi(u.w) * a1.w + b1.w);
    } else {
      #pragma unroll
      for (int j = 0; j < 8; ++j) af[j] = (__bf16)0.f;
    }
    #pragma unroll
    for (int cb = 0; cb < 8; ++cb) {
      bf16x8 bf = wsw[(kb * 8 + cb) * 64 + l];
      acc[cb] = mfma_bf16(af, bf, acc[cb]);
    }
  }
  #pragma unroll
  for (int cb = 0; cb < 8; ++cb)
    #pragma unroll
    for (int i2 = 0; i2 < 4; ++i2) {
      int orow = rbase + lk * 4 + i2;
      if (orow < N_) Y[(size_t)orow * HID + cb * 16 + lr] = bfbits(acc[cb][i2]);
    }
}

// ---------------- 128-wide aggregation + bias + relu + fused BN stats ----------------

__global__ __launch_bounds__(256) void k_aggs(const u32* __restrict__ H32,
    const int* __restrict__ rowptr, const int2* __restrict__ csr,
    const float* __restrict__ selfn, const float* __restrict__ bias,
    u32* __restrict__ out32, float* statsbuf, int* ticket,
    const float* __restrict__ gamma, const float* __restrict__ beta,
    float* aout, float* bout, int N_) {
  __shared__ float red[256][4];
  __shared__ int lastf;
  int wv = threadIdx.x >> 6, l = threadIdx.x & 63;
  int wid = blockIdx.x * 4 + wv, nw = gridDim.x * 4;
  float b0 = bias[2 * l], b1 = bias[2 * l + 1];
  float s1a = 0, s2a = 0, s1b = 0, s2b = 0;
  for (int n = wid; n < N_; n += nw) {
    u32 u = H32[(size_t)n * 64 + l];
    float sn = selfn[n];
    float a0 = sn * bf_lo(u);
    float a1 = sn * bf_hi(u);
    int e0 = rowptr[n], e1 = rowptr[n + 1];
    int e = e0;
    for (; e + 7 < e1; e += 8) {
      int2 c0 = csr[e],   c1 = csr[e+1], c2 = csr[e+2], c3 = csr[e+3];
      int2 c4 = csr[e+4], c5 = csr[e+5], c6 = csr[e+6], c7 = csr[e+7];
      u32 x0 = H32[(size_t)c0.x * 64 + l];
      u32 x1 = H32[(size_t)c1.x * 64 + l];
      u32 x2 = H32[(size_t)c2.x * 64 + l];
      u32 x3 = H32[(size_t)c3.x * 64 + l];
      u32 x4 = H32[(size_t)c4.x * 64 + l];
      u32 x5 = H32[(size_t)c5.x * 64 + l];
      u32 x6 = H32[(size_t)c6.x * 64 + l];
      u32 x7 = H32[(size_t)c7.x * 64 + l];
      a0 += __int_as_float(c0.y) * bf_lo(x0) + __int_as_float(c1.y) * bf_lo(x1)
          + __int_as_float(c2.y) * bf_lo(x2) + __int_as_float(c3.y) * bf_lo(x3)
          + __int_as_float(c4.y) * bf_lo(x4) + __int_as_float(c5.y) * bf_lo(x5)
          + __int_as_float(c6.y) * bf_lo(x6) + __int_as_float(c7.y) * bf_lo(x7);
      a1 += __int_as_float(c0.y) * bf_hi(x0) + __int_as_float(c1.y) * bf_hi(x1)
          + __int_as_float(c2.y) * bf_hi(x2) + __int_as_float(c3.y) * bf_hi(x3)
          + __int_as_float(c4.y) * bf_hi(x4) + __int_as_float(c5.y) * bf_hi(x5)
          + __int_as_float(c6.y) * bf_hi(x6) + __int_as_float(c7.y) * bf_hi(x7);
    }
    for (; e < e1; ++e) {
      int2 c0 = csr[e];
      u32 x0 = H32[(size_t)c0.x * 64 + l];
      float w0 = __int_as_float(c0.y);
      a0 += w0 * bf_lo(x0);
      a1 += w0 * bf_hi(x0);
    }
    float v0 = fmaxf(a0 + b0, 0.f), v1 = fmaxf(a1 + b1, 0.f);
    s1a += v0; s2a += v0*v0; s1b += v1; s2b += v1*v1;
    out32[(size_t)n * 64 + l] = (u32)bfbits(v0) | ((u32)bfbits(v1) << 16);
  }
  stats_tail(red, &lastf, s1a, s2a, s1b, s2b, statsbuf, ticket, gamma, beta, aout, bout, N_);
}

// ---------------- fully-fused LSTM: both layers x all timesteps ----------------
// 256 thr = 4 waves = 4 col-quarters q; block owns 32 rows (2 MFMA row-blocks/wave).
// Proven-safe register shape (R3's k_lstm2: acc[2][8], 256thr, VGPR=112, no spill).
// Gates in registers; c1/c2 in padded LDS (thread-owned, race-free); h1/h2 in LDS.

__global__ __launch_bounds__(256) void k_lstm_all(
    const u16* __restrict__ G0, const float* __restrict__ aff3, u32* __restrict__ h2out,
    const bf16x8* __restrict__ w1sw, const bf16x8* __restrict__ w2sw,
    const float* __restrict__ b1, const float* __restrict__ b2, int N_) {
  __shared__ __bf16 h1l[32][136];   // 8.5 KB, 272B stride -> 2-way bank alias (free)
  __shared__ __bf16 h2l[32][136];
  __shared__ float  c1l[32][132];   // 16.5 KB, thread-owned elements
  __shared__ float  c2l[32][132];
  int l = threadIdx.x & 63, q = threadIdx.x >> 6;   // wave = col quarter
  int lr = l & 15, lk = l >> 4;
  int r0 = blockIdx.x * 32;
  const size_t strideT = (size_t)N_ * HID;

  #pragma unroll 1
  for (int t = 0; t < TT; ++t) {
    const u16* xg = G0 + (size_t)t * strideT;
    const float* aff = aff3 + (size_t)t * 256;
    f32x4 acc[2][8];

    // ---- layer-1 gates GEMM (acc init = bias, loaded fresh each t) ----
    #pragma unroll
    for (int cb = 0; cb < 8; ++cb) {
      float b = b1[(cb >> 1) * 128 + q * 32 + (cb & 1) * 16 + lr];
      acc[0][cb] = (f32x4){b, b, b, b};
      acc[1][cb] = acc[0][cb];
    }
    #pragma unroll
    for (int kb = 0; kb < 4; ++kb) {
      int ko = kb * 32 + lk * 8;
      bf16x8 af[2];
      #pragma unroll
      for (int rb = 0; rb < 2; ++rb) {
        int row = r0 + rb * 16 + lr;
        if (row < N_) {
          uint4 u = *(const uint4*)(xg + (size_t)row * HID + ko);
          float4 a0 = *(const float4*)(aff + ko),       a1 = *(const float4*)(aff + ko + 4);
          float4 b0 = *(const float4*)(aff + HID + ko), b1v = *(const float4*)(aff + HID + ko + 4);
          af[rb][0] = (__bf16)(bf_lo(u.x) * a0.x + b0.x);
          af[rb][1] = (__bf16)(bf_hi(u.x) * a0.y + b0.y);
          af[rb][2] = (__bf16)(bf_lo(u.y) * a0.z + b0.z);
          af[rb][3] = (__bf16)(bf_hi(u.y) * a0.w + b0.w);
          af[rb][4] = (__bf16)(bf_lo(u.z) * a1.x + b1v.x);
          af[rb][5] = (__bf16)(bf_hi(u.z) * a1.y + b1v.y);
          af[rb][6] = (__bf16)(bf_lo(u.w) * a1.z + b1v.z);
          af[rb][7] = (__bf16)(bf_hi(u.w) * a1.w + b1v.w);
        } else {
          #pragma unroll
          for (int j = 0; j < 8; ++j) af[rb][j] = (__bf16)0.f;
        }
      }
      #pragma unroll
      for (int cb = 0; cb < 8; ++cb) {
        bf16x8 bf = w1sw[(size_t)(((kb * 4 + q) * 8 + cb) * 64 + l)];
        acc[0][cb] = mfma_bf16(af[0], bf, acc[0][cb]);
        acc[1][cb] = mfma_bf16(af[1], bf, acc[1][cb]);
      }
    }
    if (t > 0) {
      #pragma unroll
      for (int kb = 0; kb < 4; ++kb) {
        int ko = kb * 32 + lk * 8;
        bf16x8 af[2];
        #pragma unroll
        for (int rb = 0; rb < 2; ++rb)
          af[rb] = *(const bf16x8*)&h1l[rb * 16 + lr][ko];
        #pragma unroll
        for (int cb = 0; cb < 8; ++cb) {
          bf16x8 bf = w1sw[(size_t)((((kb + 4) * 4 + q) * 8 + cb) * 64 + l)];
          acc[0][cb] = mfma_bf16(af[0], bf, acc[0][cb]);
          acc[1][cb] = mfma_bf16(af[1], bf, acc[1][cb]);
        }
      }
    }
    __syncthreads();   // all reads of h1l(prev) done

    // ---- layer-1 cell -> c1l (thread-owned), h1l ----
    #pragma unroll
    for (int rb = 0; rb < 2; ++rb)
      #pragma unroll
      for (int i2 = 0; i2 < 4; ++i2)
        #pragma unroll
        for (int jb = 0; jb < 2; ++jb) {
          int row = rb * 16 + lk * 4 + i2;
          int col = q * 32 + jb * 16 + lr;
          float ig = acc[rb][jb][i2];
          float fg = acc[rb][2 + jb][i2];
          float gg = acc[rb][4 + jb][i2];
          float og = acc[rb][6 + jb][i2];
          float cp = (t > 0) ? c1l[row][col] : 0.f;
          float cn = sigf(fg) * cp + sigf(ig) * tanhfast(gg);
          float hn = sigf(og) * tanhfast(cn);
          c1l[row][col] = cn;
          h1l[row][col] = (__bf16)hn;
        }
    __syncthreads();   // h1l(new) visible

    // ---- layer-2 gates GEMM ----
    #pragma unroll
    for (int cb = 0; cb < 8; ++cb) {
      float b = b2[(cb >> 1) * 128 + q * 32 + (cb & 1) * 16 + lr];
      acc[0][cb] = (f32x4){b, b, b, b};
      acc[1][cb] = acc[0][cb];
    }
    #pragma unroll
    for (int kb = 0; kb < 4; ++kb) {
      int ko = kb * 32 + lk * 8;
      bf16x8 af[2];
      #pragma unroll
      for (int rb = 0; rb < 2; ++rb)
        af[rb] = *(const bf16x8*)&h1l[rb * 16 + lr][ko];
      #pragma unroll
      for (int cb = 0; cb < 8; ++cb) {
        bf16x8 bf = w2sw[(size_t)(((kb * 4 + q) * 8 + cb) * 64 + l)];
        acc[0][cb] = mfma_bf16(af[0], bf, acc[0][cb]);
        acc[1][cb] = mfma_bf16(af[1], bf, acc[1][cb]);
      }
    }
    if (t > 0) {
      #pragma unroll
      for (int kb = 0; kb < 4; ++kb) {
        int ko = kb * 32 + lk * 8;
        bf16x8 af[2];
        #pragma unroll
        for (int rb = 0; rb < 2; ++rb)
          af[rb] = *(const bf16x8*)&h2l[rb * 16 + lr][ko];
        #pragma unroll
        for (int cb = 0; cb < 8; ++cb) {
          bf16x8 bf = w2sw[(size_t)((((kb + 4) * 4 + q) * 8 + cb) * 64 + l)];
          acc[0][cb] = mfma_bf16(af[0], bf, acc[0][cb]);
          acc[1][cb] = mfma_bf16(af[1], bf, acc[1][cb]);
        }
      }
    }
    __syncthreads();   // all reads of h2l(prev) done

    // ---- layer-2 cell -> c2l, h2l ----
    #pragma unroll
    for (int rb = 0; rb < 2; ++rb)
      #pragma unroll
      for (int i2 = 0; i2 < 4; ++i2)
        #pragma unroll
        for (int jb = 0; jb < 2; ++jb) {
          int row = rb * 16 + lk * 4 + i2;
          int col = q * 32 + jb * 16 + lr;
          float ig = acc[rb][jb][i2];
          float fg = acc[rb][2 + jb][i2];
          float gg = acc[rb][4 + jb][i2];
          float og = acc[rb][6 + jb][i2];
          float cp = (t > 0) ? c2l[row][col] : 0.f;
          float cn = sigf(fg) * cp + sigf(ig) * tanhfast(gg);
          float hn = sigf(og) * tanhfast(cn);
          c2l[row][col] = cn;
          h2l[row][col] = (__bf16)hn;
        }
    __syncthreads();   // h2l(new) visible
  }

  // coalesced copy-out of final h2
  for (int idx = threadIdx.x; idx < 32 * 64; idx += 256) {
    int row = idx >> 6, l2 = idx & 63;
    int n = r0 + row;
    if (n < N_) h2out[(size_t)n * 64 + l2] = *(const u32*)&h2l[row][2 * l2];
  }
}

// ---------------- final head: out[n] = relu(h2[n]) . Wc + S . Ws + b ----------------

__global__ __launch_bounds__(256) void k_final2(const u32* __restrict__ H2,
    const float* __restrict__ Xin, const float* __restrict__ hw,
    float* __restrict__ outp, int N_) {
  int wv = threadIdx.x >> 6, l = threadIdx.x & 63;
  int wid = blockIdx.x * 4 + wv, nw = gridDim.x * 4;
  float wc0 = hw[2 * l], wc1 = hw[2 * l + 1];
  float ws0 = hw[HID], ws1 = hw[HID + 1], ws2 = hw[HID + 2], bb = hw[HID + 3];
  for (int n = wid; n < N_; n += nw) {
    u32 u = H2[(size_t)n * 64 + l];
    float p = fmaxf(bf_lo(u), 0.f) * wc0 + fmaxf(bf_hi(u), 0.f) * wc1;
    #pragma unroll
    for (int off = 32; off; off >>= 1) p += __shfl_down(p, off);
    if (l == 0) {
      p += Xin[(size_t)n * FIN] * ws0
         + Xin[((size_t)N_ + n) * FIN] * ws1
         + Xin[((size_t)2 * N_ + n) * FIN] * ws2;
      outp[n] = p + bb;
    }
  }
}

// ---------------- host ----------------

extern "C" void kernel_launch(void* const* d_in, const int* in_sizes, int n_in,
                              void* d_out, int out_size, void* d_ws, size_t ws_size,
                              hipStream_t stream) {
  const float* X   = (const float*)d_in[0];
  const int*   ei  = (const int*)  d_in[1];
  const float* ew  = (const float*)d_in[2];
  const float* w1  = (const float*)d_in[3];
  const float* wc  = (const float*)d_in[4];
  const float* bc  = (const float*)d_in[5];
  const float* gam = (const float*)d_in[6];
  const float* bet = (const float*)d_in[7];
  const float* wih = (const float*)d_in[8];
  const float* whh = (const float*)d_in[9];
  const float* lb  = (const float*)d_in[10];
  const float* l1w = (const float*)d_in[11];
  const float* l1b = (const float*)d_in[12];
  const float* l2w = (const float*)d_in[13];
  const float* l2b = (const float*)d_in[14];
  float* outp = (float*)d_out;
  (void)n_in; (void)out_size; (void)ws_size;

  const int N = in_sizes[0] / (TT * FIN);
  const int E = in_sizes[1] / 2;
  const int* srcv = ei;
  const int* dstv = ei + E;

  char* base = (char*)d_ws;
  size_t off = 0;
  auto alloc = [&](size_t b) -> void* {
    void* p = base + off;
    off += (b + 255) & ~(size_t)255;
    return p;
  };

  u64*   pk     = (u64*)  alloc((size_t)N * 8);
  int*   epos   = (int*)  alloc((size_t)E * 4);
  int*   rowptr = (int*)  alloc(((size_t)N + 1) * 4);
  int*   partial= (int*)  alloc(1024);
  float* dinv   = (float*)alloc((size_t)N * 4);
  float* selfn  = (float*)alloc((size_t)N * 4);
  int2*  csr    = (int2*) alloc((size_t)E * 8);
  float* XA     = (float*)alloc((size_t)N * 12 * 4);
  u32*   Ga     = (u32*)  alloc((size_t)N * 64 * 4);
  u32*   Gb     = (u32*)  alloc((size_t)N * 64 * 4);   // doubles as h2 final
  u32*   Gfin   = (u32*)  alloc((size_t)3 * N * 64 * 4);
  u32*   Htb    = (u32*)  alloc((size_t)N * 64 * 4);
  float* statsb = (float*)alloc(16 * 256 * 4);
  int*   ticket = (int*)  alloc(256);
  float* aff    = (float*)alloc(256 * 4);
  float* aff3   = (float*)alloc((size_t)3 * 256 * 4);
  float* hw     = (float*)alloc(136 * 4);
  bf16x8* wcsw  = (bf16x8*)alloc((size_t)3 * 2048 * 16);
  bf16x8* wstk  = (bf16x8*)alloc((size_t)2 * 16384 * 16);

  int gN = (N + 255) / 256, gE = (E + 255) / 256;
  int nb = (N + 255) / 256;

  k_init<<<gN, 256, 0, stream>>>(pk, statsb, ticket, N);
  k_deg<<<gE, 256, 0, stream>>>(dstv, ew, pk, epos, E);
  k_scanA<<<nb, 256, 0, stream>>>(pk, rowptr, partial, dinv, selfn, N);
  k_scanB<<<1, 256, 0, stream>>>(partial, nb);
  k_scanC<<<nb, 256, 0, stream>>>(rowptr, partial, N);
  k_fillcsr<<<gE, 256, 0, stream>>>(srcv, dstv, ew, dinv, rowptr, epos, csr, E);
  k_aggX<<<1024, 256, 0, stream>>>(X, rowptr, csr, selfn, XA, N);
  k_swzall<<<152, 256, 0, stream>>>(wc, wih, whh, wcsw, wstk);
  k_headprep<<<1, 256, 0, stream>>>(l1w, l1b, l2w, l2b, hw);

  for (int t = 0; t < TT; ++t) {
    u32* Gt = Gfin + (size_t)t * N * 64;
    float* afft = aff3 + (size_t)t * 256;
    k_l0s<<<512, 256, 0, stream>>>(XA, w1, bc, Ga, statsb, ticket, gam, bet,
                                   aff, aff + HID, t, N);
    k_trans<<<(N + 63) / 64, 256, 0, stream>>>((const u16*)Ga, aff, aff + HID, wcsw,
                                               (u16*)Htb, N);
    k_aggs<<<2048, 256, 0, stream>>>(Htb, rowptr, csr, selfn, bc + HID, Gb,
                                     statsb, ticket, gam + HID, bet + HID,
                                     aff, aff + HID, N);
    k_trans<<<(N + 63) / 64, 256, 0, stream>>>((const u16*)Gb, aff, aff + HID, wcsw + 2048,
                                               (u16*)Htb, N);
    k_aggs<<<2048, 256, 0, stream>>>(Htb, rowptr, csr, selfn, bc + 2 * HID, Ga,
                                     statsb, ticket, gam + 2 * HID, bet + 2 * HID,
                                     aff, aff + HID, N);
    k_trans<<<(N + 63) / 64, 256, 0, stream>>>((const u16*)Ga, aff, aff + HID, wcsw + 4096,
                                               (u16*)Htb, N);
    k_aggs<<<2048, 256, 0, stream>>>(Htb, rowptr, csr, selfn, bc + 3 * HID, Gt,
                                     statsb, ticket, gam + 3 * HID, bet + 3 * HID,
                                     afft, afft + HID, N);
  }

  k_lstm_all<<<(N + 31) / 32, 256, 0, stream>>>(
      (const u16*)Gfin, aff3, Gb, wstk, wstk + 16384, lb, lb + 512, N);

  k_final2<<<512, 256, 0, stream>>>((const u32*)Gb, X, hw, outp, N);
}

// Round 8
// 1623.892 us; speedup vs baseline: 1.6477x; 1.3554x over previous
//
#include <hip/hip_runtime.h>
#include <cstdint>

#define TT  3
#define FIN 4
#define HID 128

typedef unsigned int   u32;
typedef unsigned short u16;
typedef unsigned long long u64;
typedef float f32x4 __attribute__((ext_vector_type(4)));
typedef __bf16 bf16x8 __attribute__((ext_vector_type(8)));

static __device__ __forceinline__ f32x4 mfma_bf16(bf16x8 a, bf16x8 b, f32x4 c) {
  return __builtin_amdgcn_mfma_f32_16x16x32_bf16(a, b, c, 0, 0, 0);
}
static __device__ __forceinline__ float sigf(float v) { return 1.f / (1.f + expf(-v)); }
static __device__ __forceinline__ float bf_lo(u32 u) { return __uint_as_float(u << 16); }
static __device__ __forceinline__ float bf_hi(u32 u) { return __uint_as_float(u & 0xffff0000u); }
static __device__ __forceinline__ u16 bfbits(float f) {
  return __builtin_bit_cast(unsigned short, (__bf16)f);
}

// ---------------- graph preprocessing ----------------

__global__ void k_init(u64* pk, float* stats, int* ticket, int n) {
  int i = blockIdx.x * 256 + threadIdx.x;
  if (i < n) pk[i] = 0ull;
  if (blockIdx.x == 0) {
    stats[threadIdx.x] = 0.f;          // 256 entries
    if (threadIdx.x == 0) *ticket = 0;
  }
}

// one u64 atomic per edge: hi 22 bits = count, low 42 bits = Q10.32 weight sum.
// returned old value gives the edge its within-destination ordinal.
__global__ void k_deg(const int* __restrict__ dstv, const float* __restrict__ ew,
                      u64* pk, int* __restrict__ epos, int E_) {
  int e = blockIdx.x * 256 + threadIdx.x;
  if (e < E_) {
    int d = dstv[e];
    u64 inc = (1ull << 42) | (u64)(ew[e] * 4294967296.0f);
    u64 old = atomicAdd(&pk[d], inc);
    epos[e] = (int)(old >> 42);
  }
}

__global__ __launch_bounds__(256) void k_scanA(const u64* __restrict__ pk, int* rowptr,
    int* partial, float* dinv, float* selfn, int n) {
  __shared__ int wsum[4];
  int tid = threadIdx.x, lane = tid & 63, wv = tid >> 6;
  int i = blockIdx.x * 256 + tid;
  int v = 0;
  if (i < n) {
    u64 p = pk[i];
    v = (int)(p >> 42);
    float degw = (float)((double)(p & ((1ull << 42) - 1)) * (1.0 / 4294967296.0) + 1.0);
    float r = rsqrtf(degw);
    dinv[i] = r; selfn[i] = r * r;
  }
  int inc = v;
  #pragma unroll
  for (int off = 1; off < 64; off <<= 1) {
    int t2 = __shfl_up(inc, off);
    if (lane >= off) inc += t2;
  }
  if (lane == 63) wsum[wv] = inc;
  __syncthreads();
  if (tid == 0) {
    int s = 0;
    #pragma unroll
    for (int j = 0; j < 4; ++j) { int t3 = wsum[j]; wsum[j] = s; s += t3; }
    partial[blockIdx.x] = s;
  }
  __syncthreads();
  int excl = wsum[wv] + inc - v;
  if (i <= n) rowptr[i] = excl;
}

__global__ __launch_bounds__(256) void k_scanB(int* partial, int nb) {
  __shared__ int wsum[4];
  int tid = threadIdx.x, lane = tid & 63, wv = tid >> 6;
  int v = (tid < nb) ? partial[tid] : 0;
  int inc = v;
  #pragma unroll
  for (int off = 1; off < 64; off <<= 1) {
    int t2 = __shfl_up(inc, off);
    if (lane >= off) inc += t2;
  }
  if (lane == 63) wsum[wv] = inc;
  __syncthreads();
  if (tid == 0) {
    int s = 0;
    #pragma unroll
    for (int j = 0; j < 4; ++j) { int t3 = wsum[j]; wsum[j] = s; s += t3; }
  }
  __syncthreads();
  int excl = wsum[wv] + inc - v;
  if (tid < nb) partial[tid] = excl;
}

__global__ void k_scanC(int* rowptr, const int* __restrict__ partial, int n) {
  int i = blockIdx.x * 256 + threadIdx.x;
  if (i <= n) rowptr[i] += partial[blockIdx.x];
}

// no atomics: slot comes from epos; combined 8B scatter
__global__ void k_fillcsr(const int* __restrict__ srcv, const int* __restrict__ dstv,
                          const float* __restrict__ ew, const float* __restrict__ dinv,
                          const int* __restrict__ rowptr, const int* __restrict__ epos,
                          int2* __restrict__ csr, int E_) {
  int e = blockIdx.x * 256 + threadIdx.x;
  if (e < E_) {
    int d = dstv[e], s = srcv[e];
    int idx = rowptr[d] + epos[e];
    csr[idx] = make_int2(s, __float_as_int(dinv[s] * ew[e] * dinv[d]));
  }
}

// ---------------- layer-0: aggregate X (12 feats) ----------------

__global__ __launch_bounds__(256) void k_aggX(const float* __restrict__ X,
    const int* __restrict__ rowptr, const int2* __restrict__ csr,
    const float* __restrict__ selfn, float* __restrict__ XA, int N_) {
  int wv = threadIdx.x >> 6, l = threadIdx.x & 63;
  int wid = blockIdx.x * 4 + wv, nw = gridDim.x * 4;
  for (int n = wid; n < N_; n += nw) {
    float acc[12];
    #pragma unroll
    for (int i = 0; i < 12; ++i) acc[i] = 0.f;
    int e0 = rowptr[n], e1 = rowptr[n + 1];
    for (int e = e0 + l; e < e1; e += 64) {
      int2 v2 = csr[e];
      int s = v2.x; float wn = __int_as_float(v2.y);
      #pragma unroll
      for (int t = 0; t < TT; ++t) {
        float4 v = *(const float4*)(X + ((size_t)t * N_ + s) * FIN);
        acc[t*4+0] += wn * v.x; acc[t*4+1] += wn * v.y;
        acc[t*4+2] += wn * v.z; acc[t*4+3] += wn * v.w;
      }
    }
    #pragma unroll
    for (int i = 0; i < 12; ++i)
      for (int off = 32; off; off >>= 1) acc[i] += __shfl_down(acc[i], off);
    if (l == 0) {
      float sn = selfn[n];
      #pragma unroll
      for (int t = 0; t < TT; ++t) {
        float4 v = *(const float4*)(X + ((size_t)t * N_ + n) * FIN);
        XA[(size_t)n*12 + t*4+0] = acc[t*4+0] + sn * v.x;
        XA[(size_t)n*12 + t*4+1] = acc[t*4+1] + sn * v.y;
        XA[(size_t)n*12 + t*4+2] = acc[t*4+2] + sn * v.z;
        XA[(size_t)n*12 + t*4+3] = acc[t*4+3] + sn * v.w;
      }
    }
  }
}

__global__ void k_l0(const float* __restrict__ XA, const float* __restrict__ w1,
                     const float* __restrict__ bc0, u16* __restrict__ outp, int t, int N_) {
  int tid = blockIdx.x * 256 + threadIdx.x;
  if (tid >= N_ * 64) return;
  int n = tid >> 6, cp = (tid & 63) * 2;
  float4 x = *(const float4*)(XA + (size_t)n * 12 + t * 4);
  float s0 = bc0[cp], s1 = bc0[cp + 1];
  s0 += x.x * w1[cp]       + x.y * w1[HID + cp]     + x.z * w1[2*HID + cp]     + x.w * w1[3*HID + cp];
  s1 += x.x * w1[cp+1]     + x.y * w1[HID + cp+1]   + x.z * w1[2*HID + cp+1]   + x.w * w1[3*HID + cp+1];
  u32 o = (u32)bfbits(fmaxf(s0, 0.f)) | ((u32)bfbits(fmaxf(s1, 0.f)) << 16);
  *(u32*)(outp + (size_t)n * HID + cp) = o;
}

// ---------------- BN stats (bf16 in) + last-block computes affine ----------------

__global__ __launch_bounds__(256) void k_stats(const u16* __restrict__ H, float* stats,
    int* ticket, const float* __restrict__ gamma, const float* __restrict__ beta,
    float* aout, float* bout, int N_) {
  __shared__ float red[256][4];
  __shared__ int lastf;
  int l = threadIdx.x & 63, half = threadIdx.x >> 6;
  float s1a = 0.f, s2a = 0.f, s1b = 0.f, s2b = 0.f;
  for (int n = blockIdx.x * 4 + half; n < N_; n += gridDim.x * 4) {
    u32 u = *(const u32*)(H + (size_t)n * HID + 2 * l);
    float v0 = bf_lo(u), v1 = bf_hi(u);
    s1a += v0; s2a += v0 * v0; s1b += v1; s2b += v1 * v1;
  }
  red[threadIdx.x][0] = s1a; red[threadIdx.x][1] = s2a;
  red[threadIdx.x][2] = s1b; red[threadIdx.x][3] = s2b;
  __syncthreads();
  if (half == 0) {
    float a0 = 0, a1 = 0, a2 = 0, a3 = 0;
    #pragma unroll
    for (int h2 = 0; h2 < 4; ++h2) {
      a0 += red[h2*64 + l][0]; a1 += red[h2*64 + l][1];
      a2 += red[h2*64 + l][2]; a3 += red[h2*64 + l][3];
    }
    atomicAdd(&stats[2*l], a0);       atomicAdd(&stats[HID + 2*l], a1);
    atomicAdd(&stats[2*l + 1], a2);   atomicAdd(&stats[HID + 2*l + 1], a3);
  }
  __syncthreads();
  if (threadIdx.x == 0) {
    __threadfence();
    int t = __hip_atomic_fetch_add(ticket, 1, __ATOMIC_ACQ_REL, __HIP_MEMORY_SCOPE_AGENT);
    lastf = (t == (int)gridDim.x - 1) ? 1 : 0;
  }
  __syncthreads();
  if (lastf) {
    if (threadIdx.x < HID) {
      int c = threadIdx.x;
      float s1 = __hip_atomic_load(&stats[c],       __ATOMIC_RELAXED, __HIP_MEMORY_SCOPE_AGENT);
      float s2 = __hip_atomic_load(&stats[HID + c], __ATOMIC_RELAXED, __HIP_MEMORY_SCOPE_AGENT);
      float invn = 1.f / (float)N_;
      float mu = s1 * invn;
      float var = fmaxf(s2 * invn - mu * mu, 0.f);
      float a = gamma[c] * rsqrtf(var + 1e-5f);
      aout[c] = a;
      bout[c] = beta[c] - mu * a;
      stats[c] = 0.f; stats[HID + c] = 0.f;
    }
    if (threadIdx.x == 0) *ticket = 0;
  }
}

// ---------------- weight swizzles (one kernel) ----------------

__global__ void k_swzall(const float* __restrict__ wc, const float* __restrict__ wih,
                         const float* __restrict__ whh,
                         bf16x8* __restrict__ wcsw, bf16x8* __restrict__ wstk) {
  int id = blockIdx.x * 256 + threadIdx.x;
  if (id < 6144) {
    int i = id >> 11, lid = id & 2047;
    int l = lid & 63, frag = lid >> 6;
    int cb = frag & 7, kb = frag >> 3;
    int col = cb * 16 + (l & 15);
    int k0 = kb * 32 + (l >> 4) * 8;
    const float* W = wc + (size_t)i * HID * HID;
    bf16x8 v;
    #pragma unroll
    for (int j = 0; j < 8; ++j) v[j] = (__bf16)W[(size_t)(k0 + j) * HID + col];
    wcsw[i * 2048 + lid] = v;
  } else if (id < 6144 + 32768) {
    int id2 = id - 6144;
    int layer = id2 >> 14, lid = id2 & 16383;
    int l = lid & 63, frag = lid >> 6;
    int cb = frag & 31, kb = frag >> 5;
    int col = cb * 16 + (l & 15);
    int k0 = kb * 32 + (l >> 4) * 8;
    const float* wi = wih + (size_t)layer * 512 * HID;
    const float* wh = whh + (size_t)layer * 512 * HID;
    bf16x8 v;
    #pragma unroll
    for (int j = 0; j < 8; ++j) {
      int k = k0 + j;
      float val = (k < HID) ? wi[(size_t)col * HID + k] : wh[(size_t)col * HID + (k - HID)];
      v[j] = (__bf16)val;
    }
    wstk[layer * 16384 + lid] = v;
  }
}

// collapsed head: Wc[k] = sum_j lin1_w[k][j]*lin2_w[j]; b = lin1_b@lin2_w + lin2_b
__global__ void k_headprep(const float* __restrict__ l1w, const float* __restrict__ l1b,
                           const float* __restrict__ l2w, const float* __restrict__ l2b,
                           float* __restrict__ hw) {
  int k = threadIdx.x;
  if (k < HID + TT) {
    float s = 0.f;
    for (int j = 0; j < HID; ++j) s += l1w[(size_t)k * HID + j] * l2w[j];
    hw[k] = s;
  } else if (k == HID + TT) {
    float s = l2b[0];
    for (int j = 0; j < HID; ++j) s += l1b[j] * l2w[j];
    hw[HID + TT] = s;
  }
}

// ---------------- MFMA transform: Y = affine(bf16 X) @ W, bf16 out ----------------

__global__ __launch_bounds__(256) void k_trans(const u16* __restrict__ Xin,
    const float* __restrict__ fa, const float* __restrict__ fb,
    const bf16x8* __restrict__ wsw, u16* __restrict__ Y, int N_) {
  int w = threadIdx.x >> 6, l = threadIdx.x & 63;
  int lr = l & 15, lk = l >> 4;
  int rbase = blockIdx.x * 64 + w * 16;
  int arow = rbase + lr;
  bool av = arow < N_;
  f32x4 acc[8];
  #pragma unroll
  for (int cb = 0; cb < 8; ++cb) acc[cb] = (f32x4){0.f, 0.f, 0.f, 0.f};
  #pragma unroll
  for (int kb = 0; kb < 4; ++kb) {
    int ko = kb * 32 + lk * 8;
    bf16x8 af;
    if (av) {
      uint4 u = *(const uint4*)(Xin + (size_t)arow * HID + ko);
      float4 a0 = *(const float4*)(fa + ko), a1 = *(const float4*)(fa + ko + 4);
      float4 b0 = *(const float4*)(fb + ko), b1 = *(const float4*)(fb + ko + 4);
      af[0] = (__bf16)(bf_lo(u.x) * a0.x + b0.x);
      af[1] = (__bf16)(bf_hi(u.x) * a0.y + b0.y);
      af[2] = (__bf16)(bf_lo(u.y) * a0.z + b0.z);
      af[3] = (__bf16)(bf_hi(u.y) * a0.w + b0.w);
      af[4] = (__bf16)(bf_lo(u.z) * a1.x + b1.x);
      af[5] = (__bf16)(bf_hi(u.z) * a1.y + b1.y);
      af[6] = (__bf16)(bf_lo(u.w) * a1.z + b1.z);
      af[7] = (__bf16)(bf_hi(u.w) * a1.w + b1.w);
    } else {
      #pragma unroll
      for (int j = 0; j < 8; ++j) af[j] = (__bf16)0.f;
    }
    #pragma unroll
    for (int cb = 0; cb < 8; ++cb) {
      bf16x8 bf = wsw[(kb * 8 + cb) * 64 + l];
      acc[cb] = mfma_bf16(af, bf, acc[cb]);
    }
  }
  #pragma unroll
  for (int cb = 0; cb < 8; ++cb)
    #pragma unroll
    for (int i2 = 0; i2 < 4; ++i2) {
      int orow = rbase + lk * 4 + i2;
      if (orow < N_) Y[(size_t)orow * HID + cb * 16 + lr] = bfbits(acc[cb][i2]);
    }
}

// ---------------- 128-wide aggregation (pull, bf16 in/out) ----------------

__global__ __launch_bounds__(256) void k_agg(const u16* __restrict__ Hin,
    const int* __restrict__ rowptr, const int2* __restrict__ csr,
    const float* __restrict__ selfn, const float* __restrict__ bias,
    u16* __restrict__ outp, int N_) {
  int wv = threadIdx.x >> 6, l = threadIdx.x & 63;
  int wid = blockIdx.x * 4 + wv, nw = gridDim.x * 4;
  float b0 = bias[2 * l], b1 = bias[2 * l + 1];
  const u32* H32 = (const u32*)Hin;
  for (int n = wid; n < N_; n += nw) {
    u32 u = H32[(size_t)n * 64 + l];
    float sn = selfn[n];
    float a0 = sn * bf_lo(u);
    float a1 = sn * bf_hi(u);
    int e0 = rowptr[n], e1 = rowptr[n + 1];
    int e = e0;
    for (; e + 3 < e1; e += 4) {
      int2 c0 = csr[e], c1 = csr[e+1], c2 = csr[e+2], c3 = csr[e+3];
      u32 x0 = H32[(size_t)c0.x * 64 + l];
      u32 x1 = H32[(size_t)c1.x * 64 + l];
      u32 x2 = H32[(size_t)c2.x * 64 + l];
      u32 x3 = H32[(size_t)c3.x * 64 + l];
      float w0 = __int_as_float(c0.y), w1v = __int_as_float(c1.y);
      float w2 = __int_as_float(c2.y), w3v = __int_as_float(c3.y);
      a0 += w0 * bf_lo(x0) + w1v * bf_lo(x1) + w2 * bf_lo(x2) + w3v * bf_lo(x3);
      a1 += w0 * bf_hi(x0) + w1v * bf_hi(x1) + w2 * bf_hi(x2) + w3v * bf_hi(x3);
    }
    for (; e < e1; ++e) {
      int2 c0 = csr[e];
      u32 x0 = H32[(size_t)c0.x * 64 + l];
      float w0 = __int_as_float(c0.y);
      a0 += w0 * bf_lo(x0);
      a1 += w0 * bf_hi(x0);
    }
    u32 o = (u32)bfbits(fmaxf(a0 + b0, 0.f)) | ((u32)bfbits(fmaxf(a1 + b1, 0.f)) << 16);
    *(u32*)(outp + (size_t)n * HID + 2 * l) = o;
  }
}

// ---------------- fused LSTM step (bf16 x/h, fp32 c) ----------------

__global__ __launch_bounds__(256) void k_lstm(
    const u16* __restrict__ xb, const u16* __restrict__ hpb,
    const float* __restrict__ aff,   // [a(128) | b(128)] or nullptr
    float* __restrict__ cstate, u16* __restrict__ hout,
    const bf16x8* __restrict__ wsw, const float* __restrict__ bias,
    int first, int N_) {
  __shared__ __bf16 gl[32][512];   // 32 KiB
  int w = threadIdx.x >> 6, l = threadIdx.x & 63;
  int lr = l & 15, lk = l >> 4;
  int r0 = blockIdx.x * 32;
  f32x4 acc[2][8];
  #pragma unroll
  for (int rb = 0; rb < 2; ++rb)
    #pragma unroll
    for (int cb = 0; cb < 8; ++cb) acc[rb][cb] = (f32x4){0.f, 0.f, 0.f, 0.f};

  #pragma unroll
  for (int kb = 0; kb < 4; ++kb) {
    int ko = kb * 32 + lk * 8;
    bf16x8 af[2];
    #pragma unroll
    for (int rb = 0; rb < 2; ++rb) {
      int row = r0 + rb * 16 + lr;
      if (row < N_) {
        uint4 u = *(const uint4*)(xb + (size_t)row * HID + ko);
        if (aff) {
          float4 a0 = *(const float4*)(aff + ko),       a1 = *(const float4*)(aff + ko + 4);
          float4 b0 = *(const float4*)(aff + HID + ko), b1 = *(const float4*)(aff + HID + ko + 4);
          af[rb][0] = (__bf16)(bf_lo(u.x) * a0.x + b0.x);
          af[rb][1] = (__bf16)(bf_hi(u.x) * a0.y + b0.y);
          af[rb][2] = (__bf16)(bf_lo(u.y) * a0.z + b0.z);
          af[rb][3] = (__bf16)(bf_hi(u.y) * a0.w + b0.w);
          af[rb][4] = (__bf16)(bf_lo(u.z) * a1.x + b1.x);
          af[rb][5] = (__bf16)(bf_hi(u.z) * a1.y + b1.y);
          af[rb][6] = (__bf16)(bf_lo(u.w) * a1.z + b1.z);
          af[rb][7] = (__bf16)(bf_hi(u.w) * a1.w + b1.w);
        } else {
          af[rb] = __builtin_bit_cast(bf16x8, u);
        }
      } else {
        #pragma unroll
        for (int j = 0; j < 8; ++j) af[rb][j] = (__bf16)0.f;
      }
    }
    #pragma unroll
    for (int cb = 0; cb < 8; ++cb) {
      bf16x8 bf = wsw[(kb * 32 + w * 8 + cb) * 64 + l];
      acc[0][cb] = mfma_bf16(af[0], bf, acc[0][cb]);
      acc[1][cb] = mfma_bf16(af[1], bf, acc[1][cb]);
    }
  }
  if (!first) {
    #pragma unroll
    for (int kb = 0; kb < 4; ++kb) {
      int ko = kb * 32 + lk * 8;
      bf16x8 af[2];
      #pragma unroll
      for (int rb = 0; rb < 2; ++rb) {
        int row = r0 + rb * 16 + lr;
        if (row < N_) {
          af[rb] = __builtin_bit_cast(bf16x8, *(const uint4*)(hpb + (size_t)row * HID + ko));
        } else {
          #pragma unroll
          for (int j = 0; j < 8; ++j) af[rb][j] = (__bf16)0.f;
        }
      }
      #pragma unroll
      for (int cb = 0; cb < 8; ++cb) {
        bf16x8 bf = wsw[((kb + 4) * 32 + w * 8 + cb) * 64 + l];
        acc[0][cb] = mfma_bf16(af[0], bf, acc[0][cb]);
        acc[1][cb] = mfma_bf16(af[1], bf, acc[1][cb]);
      }
    }
  }
  #pragma unroll
  for (int rb = 0; rb < 2; ++rb)
    #pragma unroll
    for (int cb = 0; cb < 8; ++cb)
      #pragma unroll
      for (int i2 = 0; i2 < 4; ++i2)
        gl[rb * 16 + lk * 4 + i2][w * 128 + cb * 16 + lr] = (__bf16)acc[rb][cb][i2];
  __syncthreads();
  for (int it = threadIdx.x; it < 32 * HID; it += 256) {
    int nl = it >> 7, j = it & 127;
    int n = r0 + nl;
    if (n >= N_) continue;
    float ig = (float)gl[nl][j]       + bias[j];
    float fg = (float)gl[nl][128 + j] + bias[128 + j];
    float gg = (float)gl[nl][256 + j] + bias[256 + j];
    float og = (float)gl[nl][384 + j] + bias[384 + j];
    float cp = first ? 0.f : cstate[(size_t)n * HID + j];
    float cn = sigf(fg) * cp + sigf(ig) * tanhf(gg);
    float hn = sigf(og) * tanhf(cn);
    cstate[(size_t)n * HID + j] = cn;
    hout[(size_t)n * HID + j] = bfbits(hn);
  }
}

// ---------------- final head: out[n] = relu(h2[n]) . Wc + S . Ws + b ----------------

__global__ __launch_bounds__(256) void k_final2(const u32* __restrict__ H2,
    const float* __restrict__ Xin, const float* __restrict__ hw,
    float* __restrict__ outp, int N_) {
  int wv = threadIdx.x >> 6, l = threadIdx.x & 63;
  int wid = blockIdx.x * 4 + wv, nw = gridDim.x * 4;
  float wc0 = hw[2 * l], wc1 = hw[2 * l + 1];
  float ws0 = hw[HID], ws1 = hw[HID + 1], ws2 = hw[HID + 2], bb = hw[HID + 3];
  for (int n = wid; n < N_; n += nw) {
    u32 u = H2[(size_t)n * 64 + l];
    float p = fmaxf(bf_lo(u), 0.f) * wc0 + fmaxf(bf_hi(u), 0.f) * wc1;
    #pragma unroll
    for (int off = 32; off; off >>= 1) p += __shfl_down(p, off);
    if (l == 0) {
      p += Xin[(size_t)n * FIN] * ws0
         + Xin[((size_t)N_ + n) * FIN] * ws1
         + Xin[((size_t)2 * N_ + n) * FIN] * ws2;
      outp[n] = p + bb;
    }
  }
}

// ---------------- host ----------------

extern "C" void kernel_launch(void* const* d_in, const int* in_sizes, int n_in,
                              void* d_out, int out_size, void* d_ws, size_t ws_size,
                              hipStream_t stream) {
  const float* X   = (const float*)d_in[0];
  const int*   ei  = (const int*)  d_in[1];
  const float* ew  = (const float*)d_in[2];
  const float* w1  = (const float*)d_in[3];
  const float* wc  = (const float*)d_in[4];
  const float* bc  = (const float*)d_in[5];
  const float* gam = (const float*)d_in[6];
  const float* bet = (const float*)d_in[7];
  const float* wih = (const float*)d_in[8];
  const float* whh = (const float*)d_in[9];
  const float* lb  = (const float*)d_in[10];
  const float* l1w = (const float*)d_in[11];
  const float* l1b = (const float*)d_in[12];
  const float* l2w = (const float*)d_in[13];
  const float* l2b = (const float*)d_in[14];
  float* outp = (float*)d_out;
  (void)n_in; (void)out_size; (void)ws_size;

  const int N = in_sizes[0] / (TT * FIN);
  const int E = in_sizes[1] / 2;
  const int* srcv = ei;
  const int* dstv = ei + E;

  char* base = (char*)d_ws;
  size_t off = 0;
  auto alloc = [&](size_t b) -> void* {
    void* p = base + off;
    off += (b + 255) & ~(size_t)255;
    return p;
  };

  u64*   pk     = (u64*)  alloc((size_t)N * 8);
  int*   epos   = (int*)  alloc((size_t)E * 4);
  int*   rowptr = (int*)  alloc(((size_t)N + 1) * 4);
  int*   partial= (int*)  alloc(1024);
  float* dinv   = (float*)alloc((size_t)N * 4);
  float* selfn  = (float*)alloc((size_t)N * 4);
  int2*  csr    = (int2*) alloc((size_t)E * 8);
  float* XA     = (float*)alloc((size_t)N * 12 * 4);
  u16*   Ga     = (u16*)  alloc((size_t)N * HID * 2);
  u16*   Gb     = (u16*)  alloc((size_t)N * HID * 2);
  u16*   Gfin   = (u16*)  alloc((size_t)3 * N * HID * 2);
  u16*   Htb    = (u16*)  alloc((size_t)N * HID * 2);
  u16*   Cb     = (u16*)  alloc((size_t)3 * N * HID * 2);
  float* cbuf   = (float*)alloc((size_t)N * HID * 4);
  float* stats  = (float*)alloc(256 * 4);
  int*   ticket = (int*)  alloc(256);
  float* abuf   = (float*)alloc(128 * 4);
  float* bbuf   = (float*)alloc(128 * 4);
  float* aff3   = (float*)alloc((size_t)3 * 256 * 4);
  float* hw     = (float*)alloc(136 * 4);
  bf16x8* wcsw  = (bf16x8*)alloc((size_t)3 * 2048 * 16);
  bf16x8* wstk  = (bf16x8*)alloc((size_t)2 * 16384 * 16);

  int gN = (N + 255) / 256, gE = (E + 255) / 256;
  int nb = (N + 255) / 256;

  k_init<<<gN, 256, 0, stream>>>(pk, stats, ticket, N);
  k_deg<<<gE, 256, 0, stream>>>(dstv, ew, pk, epos, E);
  k_scanA<<<nb, 256, 0, stream>>>(pk, rowptr, partial, dinv, selfn, N);
  k_scanB<<<1, 256, 0, stream>>>(partial, nb);
  k_scanC<<<nb, 256, 0, stream>>>(rowptr, partial, N);
  k_fillcsr<<<gE, 256, 0, stream>>>(srcv, dstv, ew, dinv, rowptr, epos, csr, E);
  k_aggX<<<1024, 256, 0, stream>>>(X, rowptr, csr, selfn, XA, N);
  k_swzall<<<152, 256, 0, stream>>>(wc, wih, whh, wcsw, wstk);
  k_headprep<<<1, 256, 0, stream>>>(l1w, l1b, l2w, l2b, hw);

  for (int t = 0; t < TT; ++t) {
    u16* Gt = Gfin + (size_t)t * N * HID;
    float* afft = aff3 + (size_t)t * 256;
    k_l0<<<(N * 64 + 255) / 256, 256, 0, stream>>>(XA, w1, bc, Ga, t, N);
    k_stats<<<256, 256, 0, stream>>>(Ga, stats, ticket, gam, bet, abuf, bbuf, N);

    k_trans<<<(N + 63) / 64, 256, 0, stream>>>(Ga, abuf, bbuf, wcsw, (u16*)Htb, N);
    k_agg<<<2048, 256, 0, stream>>>(Htb, rowptr, csr, selfn, bc + HID, Gb, N);
    k_stats<<<256, 256, 0, stream>>>(Gb, stats, ticket, gam + HID, bet + HID, abuf, bbuf, N);

    k_trans<<<(N + 63) / 64, 256, 0, stream>>>(Gb, abuf, bbuf, wcsw + 2048, (u16*)Htb, N);
    k_agg<<<2048, 256, 0, stream>>>(Htb, rowptr, csr, selfn, bc + 2 * HID, Ga, N);
    k_stats<<<256, 256, 0, stream>>>(Ga, stats, ticket, gam + 2 * HID, bet + 2 * HID, abuf, bbuf, N);

    k_trans<<<(N + 63) / 64, 256, 0, stream>>>(Ga, abuf, bbuf, wcsw + 4096, (u16*)Htb, N);
    k_agg<<<2048, 256, 0, stream>>>(Htb, rowptr, csr, selfn, bc + 3 * HID, Gt, N);
    k_stats<<<256, 256, 0, stream>>>(Gt, stats, ticket, gam + 3 * HID, bet + 3 * HID,
                                     afft, afft + HID, N);
  }

  int gL = (N + 31) / 32;
  for (int t = 0; t < TT; ++t) {
    u16* Gt = Gfin + (size_t)t * N * HID;
    u16* Ct = Cb + (size_t)t * N * HID;
    const u16* hp = (t == 0) ? Ct : (Cb + (size_t)(t - 1) * N * HID);
    k_lstm<<<gL, 256, 0, stream>>>(Gt, hp, aff3 + (size_t)t * 256, cbuf, Ct,
                                   wstk, lb, (t == 0) ? 1 : 0, N);
  }
  for (int t = 0; t < TT; ++t) {
    u16* Ct = Cb + (size_t)t * N * HID;
    const u16* hp = (t == 0) ? Ct : (Cb + (size_t)(t - 1) * N * HID);
    k_lstm<<<gL, 256, 0, stream>>>(Ct, hp, nullptr, cbuf, Ct,
                                   wstk + 16384, lb + 512, (t == 0) ? 1 : 0, N);
  }
  k_final2<<<512, 256, 0, stream>>>((const u32*)(Cb + (size_t)2 * N * HID), X, hw, outp, N);
}

// Round 9
// 1289.408 us; speedup vs baseline: 2.0752x; 1.2594x over previous
//
#include <hip/hip_runtime.h>
#include <cstdint>

#define TT  3
#define FIN 4
#define HID 128
// t-interleaved feature row: [n][t*128+c] -> 384 u16 / 192 u32 per node
#define RS16 384
#define RS32 192

typedef unsigned int   u32;
typedef unsigned short u16;
typedef unsigned long long u64;
typedef float f32x4 __attribute__((ext_vector_type(4)));
typedef __bf16 bf16x8 __attribute__((ext_vector_type(8)));

static __device__ __forceinline__ f32x4 mfma_bf16(bf16x8 a, bf16x8 b, f32x4 c) {
  return __builtin_amdgcn_mfma_f32_16x16x32_bf16(a, b, c, 0, 0, 0);
}
static __device__ __forceinline__ float sigf(float v) { return 1.f / (1.f + expf(-v)); }
static __device__ __forceinline__ float bf_lo(u32 u) { return __uint_as_float(u << 16); }
static __device__ __forceinline__ float bf_hi(u32 u) { return __uint_as_float(u & 0xffff0000u); }
static __device__ __forceinline__ u16 bfbits(float f) {
  return __builtin_bit_cast(unsigned short, (__bf16)f);
}

// ---------------- graph preprocessing ----------------

__global__ void k_init(u64* pk, float* stats, int* ticket, int n) {
  int i = blockIdx.x * 256 + threadIdx.x;
  if (i < n) pk[i] = 0ull;
  if (blockIdx.x == 0) {
    for (int k = 0; k < 3; ++k) stats[k * 256 + threadIdx.x] = 0.f;  // 768 entries
    if (threadIdx.x == 0) *ticket = 0;
  }
}

// one u64 atomic per edge: hi 22 bits = count, low 42 bits = Q10.32 weight sum.
__global__ void k_deg(const int* __restrict__ dstv, const float* __restrict__ ew,
                      u64* pk, int* __restrict__ epos, int E_) {
  int e = blockIdx.x * 256 + threadIdx.x;
  if (e < E_) {
    int d = dstv[e];
    u64 inc = (1ull << 42) | (u64)(ew[e] * 4294967296.0f);
    u64 old = atomicAdd(&pk[d], inc);
    epos[e] = (int)(old >> 42);
  }
}

__global__ __launch_bounds__(256) void k_scanA(const u64* __restrict__ pk, int* rowptr,
    int* partial, float* dinv, float* selfn, int n) {
  __shared__ int wsum[4];
  int tid = threadIdx.x, lane = tid & 63, wv = tid >> 6;
  int i = blockIdx.x * 256 + tid;
  int v = 0;
  if (i < n) {
    u64 p = pk[i];
    v = (int)(p >> 42);
    float degw = (float)((double)(p & ((1ull << 42) - 1)) * (1.0 / 4294967296.0) + 1.0);
    float r = rsqrtf(degw);
    dinv[i] = r; selfn[i] = r * r;
  }
  int inc = v;
  #pragma unroll
  for (int off = 1; off < 64; off <<= 1) {
    int t2 = __shfl_up(inc, off);
    if (lane >= off) inc += t2;
  }
  if (lane == 63) wsum[wv] = inc;
  __syncthreads();
  if (tid == 0) {
    int s = 0;
    #pragma unroll
    for (int j = 0; j < 4; ++j) { int t3 = wsum[j]; wsum[j] = s; s += t3; }
    partial[blockIdx.x] = s;
  }
  __syncthreads();
  int excl = wsum[wv] + inc - v;
  if (i <= n) rowptr[i] = excl;
}

__global__ __launch_bounds__(256) void k_scanB(int* partial, int nb) {
  __shared__ int wsum[4];
  int tid = threadIdx.x, lane = tid & 63, wv = tid >> 6;
  int v = (tid < nb) ? partial[tid] : 0;
  int inc = v;
  #pragma unroll
  for (int off = 1; off < 64; off <<= 1) {
    int t2 = __shfl_up(inc, off);
    if (lane >= off) inc += t2;
  }
  if (lane == 63) wsum[wv] = inc;
  __syncthreads();
  if (tid == 0) {
    int s = 0;
    #pragma unroll
    for (int j = 0; j < 4; ++j) { int t3 = wsum[j]; wsum[j] = s; s += t3; }
  }
  __syncthreads();
  int excl = wsum[wv] + inc - v;
  if (tid < nb) partial[tid] = excl;
}

__global__ void k_scanC(int* rowptr, const int* __restrict__ partial, int n) {
  int i = blockIdx.x * 256 + threadIdx.x;
  if (i <= n) rowptr[i] += partial[blockIdx.x];
}

__global__ void k_fillcsr(const int* __restrict__ srcv, const int* __restrict__ dstv,
                          const float* __restrict__ ew, const float* __restrict__ dinv,
                          const int* __restrict__ rowptr, const int* __restrict__ epos,
                          int2* __restrict__ csr, int E_) {
  int e = blockIdx.x * 256 + threadIdx.x;
  if (e < E_) {
    int d = dstv[e], s = srcv[e];
    int idx = rowptr[d] + epos[e];
    csr[idx] = make_int2(s, __float_as_int(dinv[s] * ew[e] * dinv[d]));
  }
}

// ---------------- layer-0: aggregate X (12 feats) ----------------

__global__ __launch_bounds__(256) void k_aggX(const float* __restrict__ X,
    const int* __restrict__ rowptr, const int2* __restrict__ csr,
    const float* __restrict__ selfn, float* __restrict__ XA, int N_) {
  int wv = threadIdx.x >> 6, l = threadIdx.x & 63;
  int wid = blockIdx.x * 4 + wv, nw = gridDim.x * 4;
  for (int n = wid; n < N_; n += nw) {
    float acc[12];
    #pragma unroll
    for (int i = 0; i < 12; ++i) acc[i] = 0.f;
    int e0 = rowptr[n], e1 = rowptr[n + 1];
    for (int e = e0 + l; e < e1; e += 64) {
      int2 v2 = csr[e];
      int s = v2.x; float wn = __int_as_float(v2.y);
      #pragma unroll
      for (int t = 0; t < TT; ++t) {
        float4 v = *(const float4*)(X + ((size_t)t * N_ + s) * FIN);
        acc[t*4+0] += wn * v.x; acc[t*4+1] += wn * v.y;
        acc[t*4+2] += wn * v.z; acc[t*4+3] += wn * v.w;
      }
    }
    #pragma unroll
    for (int i = 0; i < 12; ++i)
      for (int off = 32; off; off >>= 1) acc[i] += __shfl_down(acc[i], off);
    if (l == 0) {
      float sn = selfn[n];
      #pragma unroll
      for (int t = 0; t < TT; ++t) {
        float4 v = *(const float4*)(X + ((size_t)t * N_ + n) * FIN);
        XA[(size_t)n*12 + t*4+0] = acc[t*4+0] + sn * v.x;
        XA[(size_t)n*12 + t*4+1] = acc[t*4+1] + sn * v.y;
        XA[(size_t)n*12 + t*4+2] = acc[t*4+2] + sn * v.z;
        XA[(size_t)n*12 + t*4+3] = acc[t*4+3] + sn * v.w;
      }
    }
  }
}

// layer-0 transform + relu, all 3 timesteps -> cat layout
__global__ void k_l0c(const float* __restrict__ XA, const float* __restrict__ w1,
                      const float* __restrict__ bc0, u32* __restrict__ out32, int N_) {
  int tid = blockIdx.x * 256 + threadIdx.x;
  if (tid >= N_ * 64) return;
  int n = tid >> 6, l = tid & 63, cp = 2 * l;
  float w00 = w1[cp],       w01 = w1[cp+1];
  float w10 = w1[HID+cp],   w11 = w1[HID+cp+1];
  float w20 = w1[2*HID+cp], w21 = w1[2*HID+cp+1];
  float w30 = w1[3*HID+cp], w31 = w1[3*HID+cp+1];
  float b0 = bc0[cp], b1 = bc0[cp+1];
  const float* xa = XA + (size_t)n * 12;
  u32* orow = out32 + (size_t)n * RS32 + l;
  #pragma unroll
  for (int t = 0; t < TT; ++t) {
    float4 x = *(const float4*)(xa + t * 4);
    float v0 = fmaxf(b0 + x.x*w00 + x.y*w10 + x.z*w20 + x.w*w30, 0.f);
    float v1 = fmaxf(b1 + x.x*w01 + x.y*w11 + x.z*w21 + x.w*w31, 0.f);
    orow[t * 64] = (u32)bfbits(v0) | ((u32)bfbits(v1) << 16);
  }
}

// ---------------- BN stats, 3 timesteps in one pass ----------------

__global__ __launch_bounds__(256) void k_stats3(const u32* __restrict__ H32, float* stats,
    int* ticket, const float* __restrict__ gamma, const float* __restrict__ beta,
    float* aff /* [3*256]: per t [a(128)|b(128)] */, int N_) {
  __shared__ float red[256][12];
  __shared__ int lastf;
  int l = threadIdx.x & 63, half = threadIdx.x >> 6;
  float s1[TT][2] = {}, s2[TT][2] = {};
  for (int n = blockIdx.x * 4 + half; n < N_; n += gridDim.x * 4) {
    const u32* row = H32 + (size_t)n * RS32 + l;
    #pragma unroll
    for (int t = 0; t < TT; ++t) {
      u32 u = row[t * 64];
      float v0 = bf_lo(u), v1 = bf_hi(u);
      s1[t][0] += v0; s2[t][0] += v0 * v0;
      s1[t][1] += v1; s2[t][1] += v1 * v1;
    }
  }
  #pragma unroll
  for (int t = 0; t < TT; ++t) {
    red[threadIdx.x][t*4+0] = s1[t][0]; red[threadIdx.x][t*4+1] = s2[t][0];
    red[threadIdx.x][t*4+2] = s1[t][1]; red[threadIdx.x][t*4+3] = s2[t][1];
  }
  __syncthreads();
  if (half == 0) {
    #pragma unroll
    for (int t = 0; t < TT; ++t) {
      float a0 = 0, a1 = 0, a2 = 0, a3 = 0;
      #pragma unroll
      for (int h2 = 0; h2 < 4; ++h2) {
        a0 += red[h2*64 + l][t*4+0]; a1 += red[h2*64 + l][t*4+1];
        a2 += red[h2*64 + l][t*4+2]; a3 += red[h2*64 + l][t*4+3];
      }
      atomicAdd(&stats[t*256 + 2*l], a0);       atomicAdd(&stats[t*256 + 128 + 2*l], a1);
      atomicAdd(&stats[t*256 + 2*l + 1], a2);   atomicAdd(&stats[t*256 + 128 + 2*l + 1], a3);
    }
  }
  __syncthreads();
  if (threadIdx.x == 0) {
    __threadfence();
    int tk = __hip_atomic_fetch_add(ticket, 1, __ATOMIC_ACQ_REL, __HIP_MEMORY_SCOPE_AGENT);
    lastf = (tk == (int)gridDim.x - 1) ? 1 : 0;
  }
  __syncthreads();
  if (lastf) {
    float invn = 1.f / (float)N_;
    for (int i = threadIdx.x; i < 384; i += 256) {
      int t = i >> 7, c = i & 127;
      float s1v = __hip_atomic_load(&stats[t*256 + c],       __ATOMIC_RELAXED, __HIP_MEMORY_SCOPE_AGENT);
      float s2v = __hip_atomic_load(&stats[t*256 + 128 + c], __ATOMIC_RELAXED, __HIP_MEMORY_SCOPE_AGENT);
      float mu = s1v * invn;
      float var = fmaxf(s2v * invn - mu * mu, 0.f);
      float a = gamma[c] * rsqrtf(var + 1e-5f);
      aff[t*256 + c] = a;
      aff[t*256 + 128 + c] = beta[c] - mu * a;
      stats[t*256 + c] = 0.f; stats[t*256 + 128 + c] = 0.f;
    }
    if (threadIdx.x == 0) *ticket = 0;
  }
}

// ---------------- weight swizzles (one kernel) ----------------

__global__ void k_swzall(const float* __restrict__ wc, const float* __restrict__ wih,
                         const float* __restrict__ whh,
                         bf16x8* __restrict__ wcsw, bf16x8* __restrict__ wstk) {
  int id = blockIdx.x * 256 + threadIdx.x;
  if (id < 6144) {
    int i = id >> 11, lid = id & 2047;
    int l = lid & 63, frag = lid >> 6;
    int cb = frag & 7, kb = frag >> 3;
    int col = cb * 16 + (l & 15);
    int k0 = kb * 32 + (l >> 4) * 8;
    const float* W = wc + (size_t)i * HID * HID;
    bf16x8 v;
    #pragma unroll
    for (int j = 0; j < 8; ++j) v[j] = (__bf16)W[(size_t)(k0 + j) * HID + col];
    wcsw[i * 2048 + lid] = v;
  } else if (id < 6144 + 32768) {
    int id2 = id - 6144;
    int layer = id2 >> 14, lid = id2 & 16383;
    int l = lid & 63, frag = lid >> 6;
    int cb = frag & 31, kb = frag >> 5;
    int col = cb * 16 + (l & 15);
    int k0 = kb * 32 + (l >> 4) * 8;
    const float* wi = wih + (size_t)layer * 512 * HID;
    const float* wh = whh + (size_t)layer * 512 * HID;
    bf16x8 v;
    #pragma unroll
    for (int j = 0; j < 8; ++j) {
      int k = k0 + j;
      float val = (k < HID) ? wi[(size_t)col * HID + k] : wh[(size_t)col * HID + (k - HID)];
      v[j] = (__bf16)val;
    }
    wstk[layer * 16384 + lid] = v;
  }
}

// collapsed head: Wc[k] = sum_j lin1_w[k][j]*lin2_w[j]; b = lin1_b@lin2_w + lin2_b
__global__ void k_headprep(const float* __restrict__ l1w, const float* __restrict__ l1b,
                           const float* __restrict__ l2w, const float* __restrict__ l2b,
                           float* __restrict__ hw) {
  int k = threadIdx.x;
  if (k < HID + TT) {
    float s = 0.f;
    for (int j = 0; j < HID; ++j) s += l1w[(size_t)k * HID + j] * l2w[j];
    hw[k] = s;
  } else if (k == HID + TT) {
    float s = l2b[0];
    for (int j = 0; j < HID; ++j) s += l1b[j] * l2w[j];
    hw[HID + TT] = s;
  }
}

// ---------------- MFMA transform, 3 timesteps (cat in/out) ----------------

__global__ __launch_bounds__(256) void k_trans3(const u16* __restrict__ Xin,
    const float* __restrict__ aff, const bf16x8* __restrict__ wsw,
    u16* __restrict__ Y, int nblk, int N_) {
  int w = threadIdx.x >> 6, l = threadIdx.x & 63;
  int lr = l & 15, lk = l >> 4;
  int t = blockIdx.x / nblk;
  int blk = blockIdx.x - t * nblk;
  int rbase = blk * 64 + w * 16;
  int arow = rbase + lr;
  bool av = arow < N_;
  const float* fa = aff + t * 256;
  const float* fb = fa + 128;
  f32x4 acc[8];
  #pragma unroll
  for (int cb = 0; cb < 8; ++cb) acc[cb] = (f32x4){0.f, 0.f, 0.f, 0.f};
  #pragma unroll
  for (int kb = 0; kb < 4; ++kb) {
    int ko = kb * 32 + lk * 8;
    bf16x8 af;
    if (av) {
      uint4 u = *(const uint4*)(Xin + (size_t)arow * RS16 + t * 128 + ko);
      float4 a0 = *(const float4*)(fa + ko), a1 = *(const float4*)(fa + ko + 4);
      float4 b0 = *(const float4*)(fb + ko), b1 = *(const float4*)(fb + ko + 4);
      af[0] = (__bf16)(bf_lo(u.x) * a0.x + b0.x);
      af[1] = (__bf16)(bf_hi(u.x) * a0.y + b0.y);
      af[2] = (__bf16)(bf_lo(u.y) * a0.z + b0.z);
      af[3] = (__bf16)(bf_hi(u.y) * a0.w + b0.w);
      af[4] = (__bf16)(bf_lo(u.z) * a1.x + b1.x);
      af[5] = (__bf16)(bf_hi(u.z) * a1.y + b1.y);
      af[6] = (__bf16)(bf_lo(u.w) * a1.z + b1.z);
      af[7] = (__bf16)(bf_hi(u.w) * a1.w + b1.w);
    } else {
      #pragma unroll
      for (int j = 0; j < 8; ++j) af[j] = (__bf16)0.f;
    }
    #pragma unroll
    for (int cb = 0; cb < 8; ++cb) {
      bf16x8 bf = wsw[(kb * 8 + cb) * 64 + l];
      acc[cb] = mfma_bf16(af, bf, acc[cb]);
    }
  }
  #pragma unroll
  for (int cb = 0; cb < 8; ++cb)
    #pragma unroll
    for (int i2 = 0; i2 < 4; ++i2) {
      int orow = rbase + lk * 4 + i2;
      if (orow < N_) Y[(size_t)orow * RS16 + t * 128 + cb * 16 + lr] = bfbits(acc[cb][i2]);
    }
}

// ---------------- 3-timestep aggregation (pull, cat bf16 in/out) ----------------

__global__ __launch_bounds__(256) void k_agg3(const u16* __restrict__ Hin,
    const int* __restrict__ rowptr, const int2* __restrict__ csr,
    const float* __restrict__ selfn, const float* __restrict__ bias,
    u16* __restrict__ outp, int N_) {
  int wv = threadIdx.x >> 6, l = threadIdx.x & 63;
  int wid = blockIdx.x * 4 + wv, nw = gridDim.x * 4;
  float b0 = bias[2 * l], b1 = bias[2 * l + 1];
  const u32* H32 = (const u32*)Hin;
  u32* O32 = (u32*)outp;
  for (int n = wid; n < N_; n += nw) {
    const u32* self = H32 + (size_t)n * RS32 + l;
    float sn = selfn[n];
    u32 u0 = self[0], u1 = self[64], u2 = self[128];
    float a00 = sn * bf_lo(u0), a01 = sn * bf_hi(u0);
    float a10 = sn * bf_lo(u1), a11 = sn * bf_hi(u1);
    float a20 = sn * bf_lo(u2), a21 = sn * bf_hi(u2);
    int e0 = rowptr[n], e1 = rowptr[n + 1];
    int e = e0;
    for (; e + 3 < e1; e += 4) {
      int2 c0 = csr[e], c1 = csr[e+1], c2 = csr[e+2], c3 = csr[e+3];
      const u32* p0 = H32 + (size_t)c0.x * RS32 + l;
      const u32* p1 = H32 + (size_t)c1.x * RS32 + l;
      const u32* p2 = H32 + (size_t)c2.x * RS32 + l;
      const u32* p3 = H32 + (size_t)c3.x * RS32 + l;
      u32 x00 = p0[0], x01 = p0[64], x02 = p0[128];
      u32 x10 = p1[0], x11 = p1[64], x12 = p1[128];
      u32 x20 = p2[0], x21 = p2[64], x22 = p2[128];
      u32 x30 = p3[0], x31 = p3[64], x32 = p3[128];
      float w0 = __int_as_float(c0.y), w1v = __int_as_float(c1.y);
      float w2 = __int_as_float(c2.y), w3v = __int_as_float(c3.y);
      a00 += w0 * bf_lo(x00) + w1v * bf_lo(x10) + w2 * bf_lo(x20) + w3v * bf_lo(x30);
      a01 += w0 * bf_hi(x00) + w1v * bf_hi(x10) + w2 * bf_hi(x20) + w3v * bf_hi(x30);
      a10 += w0 * bf_lo(x01) + w1v * bf_lo(x11) + w2 * bf_lo(x21) + w3v * bf_lo(x31);
      a11 += w0 * bf_hi(x01) + w1v * bf_hi(x11) + w2 * bf_hi(x21) + w3v * bf_hi(x31);
      a20 += w0 * bf_lo(x02) + w1v * bf_lo(x12) + w2 * bf_lo(x22) + w3v * bf_lo(x32);
      a21 += w0 * bf_hi(x02) + w1v * bf_hi(x12) + w2 * bf_hi(x22) + w3v * bf_hi(x32);
    }
    for (; e < e1; ++e) {
      int2 c0 = csr[e];
      const u32* p0 = H32 + (size_t)c0.x * RS32 + l;
      u32 x00 = p0[0], x01 = p0[64], x02 = p0[128];
      float w0 = __int_as_float(c0.y);
      a00 += w0 * bf_lo(x00); a01 += w0 * bf_hi(x00);
      a10 += w0 * bf_lo(x01); a11 += w0 * bf_hi(x01);
      a20 += w0 * bf_lo(x02); a21 += w0 * bf_hi(x02);
    }
    u32* orow = O32 + (size_t)n * RS32 + l;
    orow[0]   = (u32)bfbits(fmaxf(a00 + b0, 0.f)) | ((u32)bfbits(fmaxf(a01 + b1, 0.f)) << 16);
    orow[64]  = (u32)bfbits(fmaxf(a10 + b0, 0.f)) | ((u32)bfbits(fmaxf(a11 + b1, 0.f)) << 16);
    orow[128] = (u32)bfbits(fmaxf(a20 + b0, 0.f)) | ((u32)bfbits(fmaxf(a21 + b1, 0.f)) << 16);
  }
}

// ---------------- fused LSTM step (bf16 x/h, fp32 c); x has stride xs ----------------

__global__ __launch_bounds__(256) void k_lstm(
    const u16* __restrict__ xb, int xs, const u16* __restrict__ hpb,
    const float* __restrict__ aff,   // [a(128) | b(128)] or nullptr
    float* __restrict__ cstate, u16* __restrict__ hout,
    const bf16x8* __restrict__ wsw, const float* __restrict__ bias,
    int first, int N_) {
  __shared__ __bf16 gl[32][512];   // 32 KiB
  int w = threadIdx.x >> 6, l = threadIdx.x & 63;
  int lr = l & 15, lk = l >> 4;
  int r0 = blockIdx.x * 32;
  f32x4 acc[2][8];
  #pragma unroll
  for (int rb = 0; rb < 2; ++rb)
    #pragma unroll
    for (int cb = 0; cb < 8; ++cb) acc[rb][cb] = (f32x4){0.f, 0.f, 0.f, 0.f};

  #pragma unroll
  for (int kb = 0; kb < 4; ++kb) {
    int ko = kb * 32 + lk * 8;
    bf16x8 af[2];
    #pragma unroll
    for (int rb = 0; rb < 2; ++rb) {
      int row = r0 + rb * 16 + lr;
      if (row < N_) {
        uint4 u = *(const uint4*)(xb + (size_t)row * xs + ko);
        if (aff) {
          float4 a0 = *(const float4*)(aff + ko),       a1 = *(const float4*)(aff + ko + 4);
          float4 b0 = *(const float4*)(aff + HID + ko), b1 = *(const float4*)(aff + HID + ko + 4);
          af[rb][0] = (__bf16)(bf_lo(u.x) * a0.x + b0.x);
          af[rb][1] = (__bf16)(bf_hi(u.x) * a0.y + b0.y);
          af[rb][2] = (__bf16)(bf_lo(u.y) * a0.z + b0.z);
          af[rb][3] = (__bf16)(bf_hi(u.y) * a0.w + b0.w);
          af[rb][4] = (__bf16)(bf_lo(u.z) * a1.x + b1.x);
          af[rb][5] = (__bf16)(bf_hi(u.z) * a1.y + b1.y);
          af[rb][6] = (__bf16)(bf_lo(u.w) * a1.z + b1.z);
          af[rb][7] = (__bf16)(bf_hi(u.w) * a1.w + b1.w);
        } else {
          af[rb] = __builtin_bit_cast(bf16x8, u);
        }
      } else {
        #pragma unroll
        for (int j = 0; j < 8; ++j) af[rb][j] = (__bf16)0.f;
      }
    }
    #pragma unroll
    for (int cb = 0; cb < 8; ++cb) {
      bf16x8 bf = wsw[(kb * 32 + w * 8 + cb) * 64 + l];
      acc[0][cb] = mfma_bf16(af[0], bf, acc[0][cb]);
      acc[1][cb] = mfma_bf16(af[1], bf, acc[1][cb]);
    }
  }
  if (!first) {
    #pragma unroll
    for (int kb = 0; kb < 4; ++kb) {
      int ko = kb * 32 + lk * 8;
      bf16x8 af[2];
      #pragma unroll
      for (int rb = 0; rb < 2; ++rb) {
        int row = r0 + rb * 16 + lr;
        if (row < N_) {
          af[rb] = __builtin_bit_cast(bf16x8, *(const uint4*)(hpb + (size_t)row * HID + ko));
        } else {
          #pragma unroll
          for (int j = 0; j < 8; ++j) af[rb][j] = (__bf16)0.f;
        }
      }
      #pragma unroll
      for (int cb = 0; cb < 8; ++cb) {
        bf16x8 bf = wsw[((kb + 4) * 32 + w * 8 + cb) * 64 + l];
        acc[0][cb] = mfma_bf16(af[0], bf, acc[0][cb]);
        acc[1][cb] = mfma_bf16(af[1], bf, acc[1][cb]);
      }
    }
  }
  #pragma unroll
  for (int rb = 0; rb < 2; ++rb)
    #pragma unroll
    for (int cb = 0; cb < 8; ++cb)
      #pragma unroll
      for (int i2 = 0; i2 < 4; ++i2)
        gl[rb * 16 + lk * 4 + i2][w * 128 + cb * 16 + lr] = (__bf16)acc[rb][cb][i2];
  __syncthreads();
  for (int it = threadIdx.x; it < 32 * HID; it += 256) {
    int nl = it >> 7, j = it & 127;
    int n = r0 + nl;
    if (n >= N_) continue;
    float ig = (float)gl[nl][j]       + bias[j];
    float fg = (float)gl[nl][128 + j] + bias[128 + j];
    float gg = (float)gl[nl][256 + j] + bias[256 + j];
    float og = (float)gl[nl][384 + j] + bias[384 + j];
    float cp = first ? 0.f : cstate[(size_t)n * HID + j];
    float cn = sigf(fg) * cp + sigf(ig) * tanhf(gg);
    float hn = sigf(og) * tanhf(cn);
    cstate[(size_t)n * HID + j] = cn;
    hout[(size_t)n * HID + j] = bfbits(hn);
  }
}

// ---------------- final head: out[n] = relu(h2[n]) . Wc + S . Ws + b ----------------

__global__ __launch_bounds__(256) void k_final2(const u32* __restrict__ H2,
    const float* __restrict__ Xin, const float* __restrict__ hw,
    float* __restrict__ outp, int N_) {
  int wv = threadIdx.x >> 6, l = threadIdx.x & 63;
  int wid = blockIdx.x * 4 + wv, nw = gridDim.x * 4;
  float wc0 = hw[2 * l], wc1 = hw[2 * l + 1];
  float ws0 = hw[HID], ws1 = hw[HID + 1], ws2 = hw[HID + 2], bb = hw[HID + 3];
  for (int n = wid; n < N_; n += nw) {
    u32 u = H2[(size_t)n * 64 + l];
    float p = fmaxf(bf_lo(u), 0.f) * wc0 + fmaxf(bf_hi(u), 0.f) * wc1;
    #pragma unroll
    for (int off = 32; off; off >>= 1) p += __shfl_down(p, off);
    if (l == 0) {
      p += Xin[(size_t)n * FIN] * ws0
         + Xin[((size_t)N_ + n) * FIN] * ws1
         + Xin[((size_t)2 * N_ + n) * FIN] * ws2;
      outp[n] = p + bb;
    }
  }
}

// ---------------- host ----------------

extern "C" void kernel_launch(void* const* d_in, const int* in_sizes, int n_in,
                              void* d_out, int out_size, void* d_ws, size_t ws_size,
                              hipStream_t stream) {
  const float* X   = (const float*)d_in[0];
  const int*   ei  = (const int*)  d_in[1];
  const float* ew  = (const float*)d_in[2];
  const float* w1  = (const float*)d_in[3];
  const float* wc  = (const float*)d_in[4];
  const float* bc  = (const float*)d_in[5];
  const float* gam = (const float*)d_in[6];
  const float* bet = (const float*)d_in[7];
  const float* wih = (const float*)d_in[8];
  const float* whh = (const float*)d_in[9];
  const float* lb  = (const float*)d_in[10];
  const float* l1w = (const float*)d_in[11];
  const float* l1b = (const float*)d_in[12];
  const float* l2w = (const float*)d_in[13];
  const float* l2b = (const float*)d_in[14];
  float* outp = (float*)d_out;
  (void)n_in; (void)out_size; (void)ws_size;

  const int N = in_sizes[0] / (TT * FIN);
  const int E = in_sizes[1] / 2;
  const int* srcv = ei;
  const int* dstv = ei + E;

  char* base = (char*)d_ws;
  size_t off = 0;
  auto alloc = [&](size_t b) -> void* {
    void* p = base + off;
    off += (b + 255) & ~(size_t)255;
    return p;
  };

  u64*   pk     = (u64*)  alloc((size_t)N * 8);
  int*   epos   = (int*)  alloc((size_t)E * 4);
  int*   rowptr = (int*)  alloc(((size_t)N + 1) * 4);
  int*   partial= (int*)  alloc(1024);
  float* dinv   = (float*)alloc((size_t)N * 4);
  float* selfn  = (float*)alloc((size_t)N * 4);
  int2*  csr    = (int2*) alloc((size_t)E * 8);
  float* XA     = (float*)alloc((size_t)N * 12 * 4);
  u16*   Ga     = (u16*)  alloc((size_t)N * RS16 * 2);   // cat layouts
  u16*   Gb     = (u16*)  alloc((size_t)N * RS16 * 2);
  u16*   Htb    = (u16*)  alloc((size_t)N * RS16 * 2);
  u16*   Gcat   = (u16*)  alloc((size_t)N * RS16 * 2);
  float* stats  = (float*)alloc(768 * 4);
  int*   ticket = (int*)  alloc(256);
  float* affA   = (float*)alloc((size_t)3 * 256 * 4);
  float* aff3   = (float*)alloc((size_t)3 * 256 * 4);
  float* hw     = (float*)alloc(136 * 4);
  bf16x8* wcsw  = (bf16x8*)alloc((size_t)3 * 2048 * 16);
  bf16x8* wstk  = (bf16x8*)alloc((size_t)2 * 16384 * 16);
  // aliases: GCN ping-pong buffers are dead once LSTM starts
  u16*   Cb     = Ga;                    // 3*N*128*2 = N*RS16*2 bytes exactly
  float* cbuf   = (float*)Gb;            // N*128*4 <= N*RS16*2

  int gN = (N + 255) / 256, gE = (E + 255) / 256;
  int nb = (N + 255) / 256;
  int nblk = (N + 63) / 64;

  k_init<<<gN, 256, 0, stream>>>(pk, stats, ticket, N);
  k_deg<<<gE, 256, 0, stream>>>(dstv, ew, pk, epos, E);
  k_scanA<<<nb, 256, 0, stream>>>(pk, rowptr, partial, dinv, selfn, N);
  k_scanB<<<1, 256, 0, stream>>>(partial, nb);
  k_scanC<<<nb, 256, 0, stream>>>(rowptr, partial, N);
  k_fillcsr<<<gE, 256, 0, stream>>>(srcv, dstv, ew, dinv, rowptr, epos, csr, E);
  k_aggX<<<1024, 256, 0, stream>>>(X, rowptr, csr, selfn, XA, N);
  k_swzall<<<152, 256, 0, stream>>>(wc, wih, whh, wcsw, wstk);
  k_headprep<<<1, 256, 0, stream>>>(l1w, l1b, l2w, l2b, hw);

  // GCN chain, all 3 timesteps per launch
  k_l0c<<<(N * 64 + 255) / 256, 256, 0, stream>>>(XA, w1, bc, (u32*)Ga, N);
  k_stats3<<<256, 256, 0, stream>>>((const u32*)Ga, stats, ticket, gam, bet, affA, N);

  k_trans3<<<3 * nblk, 256, 0, stream>>>(Ga, affA, wcsw, Htb, nblk, N);
  k_agg3<<<2048, 256, 0, stream>>>(Htb, rowptr, csr, selfn, bc + HID, Gb, N);
  k_stats3<<<256, 256, 0, stream>>>((const u32*)Gb, stats, ticket, gam + HID, bet + HID, affA, N);

  k_trans3<<<3 * nblk, 256, 0, stream>>>(Gb, affA, wcsw + 2048, Htb, nblk, N);
  k_agg3<<<2048, 256, 0, stream>>>(Htb, rowptr, csr, selfn, bc + 2 * HID, Gb, N);
  k_stats3<<<256, 256, 0, stream>>>((const u32*)Gb, stats, ticket, gam + 2 * HID, bet + 2 * HID, affA, N);

  k_trans3<<<3 * nblk, 256, 0, stream>>>(Gb, affA, wcsw + 4096, Htb, nblk, N);
  k_agg3<<<2048, 256, 0, stream>>>(Htb, rowptr, csr, selfn, bc + 3 * HID, Gcat, N);
  k_stats3<<<256, 256, 0, stream>>>((const u32*)Gcat, stats, ticket, gam + 3 * HID, bet + 3 * HID, aff3, N);

  // LSTM (Cb aliases Ga, cbuf aliases Gb — both GCN buffers dead now)
  int gL = (N + 31) / 32;
  for (int t = 0; t < TT; ++t) {
    u16* Ct = Cb + (size_t)t * N * HID;
    const u16* hp = (t == 0) ? Ct : (Cb + (size_t)(t - 1) * N * HID);
    k_lstm<<<gL, 256, 0, stream>>>(Gcat + (size_t)t * HID, RS16, hp,
                                   aff3 + (size_t)t * 256, cbuf, Ct,
                                   wstk, lb, (t == 0) ? 1 : 0, N);
  }
  for (int t = 0; t < TT; ++t) {
    u16* Ct = Cb + (size_t)t * N * HID;
    const u16* hp = (t == 0) ? Ct : (Cb + (size_t)(t - 1) * N * HID);
    k_lstm<<<gL, 256, 0, stream>>>(Ct, HID, hp, nullptr, cbuf, Ct,
                                   wstk + 16384, lb + 512, (t == 0) ? 1 : 0, N);
  }
  k_final2<<<512, 256, 0, stream>>>((const u32*)(Cb + (size_t)2 * N * HID), X, hw, outp, N);
}

// Round 10
// 1069.118 us; speedup vs baseline: 2.5027x; 1.2060x over previous
//
#include <hip/hip_runtime.h>
#include <hip/hip_fp8.h>
#include <cstdint>

#define TT  3
#define FIN 4
#define HID 128
// t-interleaved bf16 feature row: [n][t*128+c] -> 384 u16 / 192 u32 per node
#define RS16 384
#define RS32 192
// fp8 gather table row: 384 bytes
#define RS8  384

typedef unsigned int   u32;
typedef unsigned short u16;
typedef unsigned char  u8;
typedef unsigned long long u64;
typedef float f32x4 __attribute__((ext_vector_type(4)));
typedef __bf16 bf16x8 __attribute__((ext_vector_type(8)));

static __device__ __forceinline__ f32x4 mfma_bf16(bf16x8 a, bf16x8 b, f32x4 c) {
  return __builtin_amdgcn_mfma_f32_16x16x32_bf16(a, b, c, 0, 0, 0);
}
static __device__ __forceinline__ float sigf(float v) { return 1.f / (1.f + expf(-v)); }
static __device__ __forceinline__ float bf_lo(u32 u) { return __uint_as_float(u << 16); }
static __device__ __forceinline__ float bf_hi(u32 u) { return __uint_as_float(u & 0xffff0000u); }
static __device__ __forceinline__ u16 bfbits(float f) {
  return __builtin_bit_cast(unsigned short, (__bf16)f);
}
static __device__ __forceinline__ u8 f_to_fp8(float f) {
  __hip_fp8_e4m3 v(f); return (u8)v.__x;
}
static __device__ __forceinline__ float fp8_to_f(u8 b) {
  __hip_fp8_e4m3 v; v.__x = (__hip_fp8_storage_t)b; return (float)v;
}

// ---------------- graph preprocessing ----------------

__global__ void k_init(u64* pk, float* stats, int* ticket, int n) {
  int i = blockIdx.x * 256 + threadIdx.x;
  if (i < n) pk[i] = 0ull;
  if (blockIdx.x == 0) {
    for (int k = 0; k < 3; ++k) stats[k * 256 + threadIdx.x] = 0.f;  // 768 entries
    if (threadIdx.x == 0) *ticket = 0;
  }
}

// one u64 atomic per edge: hi 22 bits = count, low 42 bits = Q10.32 weight sum.
__global__ void k_deg(const int* __restrict__ dstv, const float* __restrict__ ew,
                      u64* pk, int* __restrict__ epos, int E_) {
  int e = blockIdx.x * 256 + threadIdx.x;
  if (e < E_) {
    int d = dstv[e];
    u64 inc = (1ull << 42) | (u64)(ew[e] * 4294967296.0f);
    u64 old = atomicAdd(&pk[d], inc);
    epos[e] = (int)(old >> 42);
  }
}

__global__ __launch_bounds__(256) void k_scanA(const u64* __restrict__ pk, int* rowptr,
    int* partial, float* dinv, float* selfn, int n) {
  __shared__ int wsum[4];
  int tid = threadIdx.x, lane = tid & 63, wv = tid >> 6;
  int i = blockIdx.x * 256 + tid;
  int v = 0;
  if (i < n) {
    u64 p = pk[i];
    v = (int)(p >> 42);
    float degw = (float)((double)(p & ((1ull << 42) - 1)) * (1.0 / 4294967296.0) + 1.0);
    float r = rsqrtf(degw);
    dinv[i] = r; selfn[i] = r * r;
  }
  int inc = v;
  #pragma unroll
  for (int off = 1; off < 64; off <<= 1) {
    int t2 = __shfl_up(inc, off);
    if (lane >= off) inc += t2;
  }
  if (lane == 63) wsum[wv] = inc;
  __syncthreads();
  if (tid == 0) {
    int s = 0;
    #pragma unroll
    for (int j = 0; j < 4; ++j) { int t3 = wsum[j]; wsum[j] = s; s += t3; }
    partial[blockIdx.x] = s;
  }
  __syncthreads();
  int excl = wsum[wv] + inc - v;
  if (i <= n) rowptr[i] = excl;
}

__global__ __launch_bounds__(256) void k_scanB(int* partial, int nb) {
  __shared__ int wsum[4];
  int tid = threadIdx.x, lane = tid & 63, wv = tid >> 6;
  int v = (tid < nb) ? partial[tid] : 0;
  int inc = v;
  #pragma unroll
  for (int off = 1; off < 64; off <<= 1) {
    int t2 = __shfl_up(inc, off);
    if (lane >= off) inc += t2;
  }
  if (lane == 63) wsum[wv] = inc;
  __syncthreads();
  if (tid == 0) {
    int s = 0;
    #pragma unroll
    for (int j = 0; j < 4; ++j) { int t3 = wsum[j]; wsum[j] = s; s += t3; }
  }
  __syncthreads();
  int excl = wsum[wv] + inc - v;
  if (tid < nb) partial[tid] = excl;
}

__global__ void k_scanC(int* rowptr, const int* __restrict__ partial, int n) {
  int i = blockIdx.x * 256 + threadIdx.x;
  if (i <= n) rowptr[i] += partial[blockIdx.x];
}

__global__ void k_fillcsr(const int* __restrict__ srcv, const int* __restrict__ dstv,
                          const float* __restrict__ ew, const float* __restrict__ dinv,
                          const int* __restrict__ rowptr, const int* __restrict__ epos,
                          int2* __restrict__ csr, int E_) {
  int e = blockIdx.x * 256 + threadIdx.x;
  if (e < E_) {
    int d = dstv[e], s = srcv[e];
    int idx = rowptr[d] + epos[e];
    csr[idx] = make_int2(s, __float_as_int(dinv[s] * ew[e] * dinv[d]));
  }
}

// ---------------- layer-0: aggregate X (12 feats) ----------------

__global__ __launch_bounds__(256) void k_aggX(const float* __restrict__ X,
    const int* __restrict__ rowptr, const int2* __restrict__ csr,
    const float* __restrict__ selfn, float* __restrict__ XA, int N_) {
  int wv = threadIdx.x >> 6, l = threadIdx.x & 63;
  int wid = blockIdx.x * 4 + wv, nw = gridDim.x * 4;
  for (int n = wid; n < N_; n += nw) {
    float acc[12];
    #pragma unroll
    for (int i = 0; i < 12; ++i) acc[i] = 0.f;
    int e0 = rowptr[n], e1 = rowptr[n + 1];
    for (int e = e0 + l; e < e1; e += 64) {
      int2 v2 = csr[e];
      int s = v2.x; float wn = __int_as_float(v2.y);
      #pragma unroll
      for (int t = 0; t < TT; ++t) {
        float4 v = *(const float4*)(X + ((size_t)t * N_ + s) * FIN);
        acc[t*4+0] += wn * v.x; acc[t*4+1] += wn * v.y;
        acc[t*4+2] += wn * v.z; acc[t*4+3] += wn * v.w;
      }
    }
    #pragma unroll
    for (int i = 0; i < 12; ++i)
      for (int off = 32; off; off >>= 1) acc[i] += __shfl_down(acc[i], off);
    if (l == 0) {
      float sn = selfn[n];
      #pragma unroll
      for (int t = 0; t < TT; ++t) {
        float4 v = *(const float4*)(X + ((size_t)t * N_ + n) * FIN);
        XA[(size_t)n*12 + t*4+0] = acc[t*4+0] + sn * v.x;
        XA[(size_t)n*12 + t*4+1] = acc[t*4+1] + sn * v.y;
        XA[(size_t)n*12 + t*4+2] = acc[t*4+2] + sn * v.z;
        XA[(size_t)n*12 + t*4+3] = acc[t*4+3] + sn * v.w;
      }
    }
  }
}

// layer-0 transform + relu, all 3 timesteps -> cat layout
__global__ void k_l0c(const float* __restrict__ XA, const float* __restrict__ w1,
                      const float* __restrict__ bc0, u32* __restrict__ out32, int N_) {
  int tid = blockIdx.x * 256 + threadIdx.x;
  if (tid >= N_ * 64) return;
  int n = tid >> 6, l = tid & 63, cp = 2 * l;
  float w00 = w1[cp],       w01 = w1[cp+1];
  float w10 = w1[HID+cp],   w11 = w1[HID+cp+1];
  float w20 = w1[2*HID+cp], w21 = w1[2*HID+cp+1];
  float w30 = w1[3*HID+cp], w31 = w1[3*HID+cp+1];
  float b0 = bc0[cp], b1 = bc0[cp+1];
  const float* xa = XA + (size_t)n * 12;
  u32* orow = out32 + (size_t)n * RS32 + l;
  #pragma unroll
  for (int t = 0; t < TT; ++t) {
    float4 x = *(const float4*)(xa + t * 4);
    float v0 = fmaxf(b0 + x.x*w00 + x.y*w10 + x.z*w20 + x.w*w30, 0.f);
    float v1 = fmaxf(b1 + x.x*w01 + x.y*w11 + x.z*w21 + x.w*w31, 0.f);
    orow[t * 64] = (u32)bfbits(v0) | ((u32)bfbits(v1) << 16);
  }
}

// ---------------- BN stats, 3 timesteps in one pass ----------------

__global__ __launch_bounds__(256) void k_stats3(const u32* __restrict__ H32, float* stats,
    int* ticket, const float* __restrict__ gamma, const float* __restrict__ beta,
    float* aff /* [3*256]: per t [a(128)|b(128)] */, int N_) {
  __shared__ float red[256][12];
  __shared__ int lastf;
  int l = threadIdx.x & 63, half = threadIdx.x >> 6;
  float s1[TT][2] = {}, s2[TT][2] = {};
  for (int n = blockIdx.x * 4 + half; n < N_; n += gridDim.x * 4) {
    const u32* row = H32 + (size_t)n * RS32 + l;
    #pragma unroll
    for (int t = 0; t < TT; ++t) {
      u32 u = row[t * 64];
      float v0 = bf_lo(u), v1 = bf_hi(u);
      s1[t][0] += v0; s2[t][0] += v0 * v0;
      s1[t][1] += v1; s2[t][1] += v1 * v1;
    }
  }
  #pragma unroll
  for (int t = 0; t < TT; ++t) {
    red[threadIdx.x][t*4+0] = s1[t][0]; red[threadIdx.x][t*4+1] = s2[t][0];
    red[threadIdx.x][t*4+2] = s1[t][1]; red[threadIdx.x][t*4+3] = s2[t][1];
  }
  __syncthreads();
  if (half == 0) {
    #pragma unroll
    for (int t = 0; t < TT; ++t) {
      float a0 = 0, a1 = 0, a2 = 0, a3 = 0;
      #pragma unroll
      for (int h2 = 0; h2 < 4; ++h2) {
        a0 += red[h2*64 + l][t*4+0]; a1 += red[h2*64 + l][t*4+1];
        a2 += red[h2*64 + l][t*4+2]; a3 += red[h2*64 + l][t*4+3];
      }
      atomicAdd(&stats[t*256 + 2*l], a0);       atomicAdd(&stats[t*256 + 128 + 2*l], a1);
      atomicAdd(&stats[t*256 + 2*l + 1], a2);   atomicAdd(&stats[t*256 + 128 + 2*l + 1], a3);
    }
  }
  __syncthreads();
  if (threadIdx.x == 0) {
    __threadfence();
    int tk = __hip_atomic_fetch_add(ticket, 1, __ATOMIC_ACQ_REL, __HIP_MEMORY_SCOPE_AGENT);
    lastf = (tk == (int)gridDim.x - 1) ? 1 : 0;
  }
  __syncthreads();
  if (lastf) {
    float invn = 1.f / (float)N_;
    for (int i = threadIdx.x; i < 384; i += 256) {
      int t = i >> 7, c = i & 127;
      float s1v = __hip_atomic_load(&stats[t*256 + c],       __ATOMIC_RELAXED, __HIP_MEMORY_SCOPE_AGENT);
      float s2v = __hip_atomic_load(&stats[t*256 + 128 + c], __ATOMIC_RELAXED, __HIP_MEMORY_SCOPE_AGENT);
      float mu = s1v * invn;
      float var = fmaxf(s2v * invn - mu * mu, 0.f);
      float a = gamma[c] * rsqrtf(var + 1e-5f);
      aff[t*256 + c] = a;
      aff[t*256 + 128 + c] = beta[c] - mu * a;
      stats[t*256 + c] = 0.f; stats[t*256 + 128 + c] = 0.f;
    }
    if (threadIdx.x == 0) *ticket = 0;
  }
}

// ---------------- weight swizzles (one kernel) ----------------

__global__ void k_swzall(const float* __restrict__ wc, const float* __restrict__ wih,
                         const float* __restrict__ whh,
                         bf16x8* __restrict__ wcsw, bf16x8* __restrict__ wstk) {
  int id = blockIdx.x * 256 + threadIdx.x;
  if (id < 6144) {
    int i = id >> 11, lid = id & 2047;
    int l = lid & 63, frag = lid >> 6;
    int cb = frag & 7, kb = frag >> 3;
    int col = cb * 16 + (l & 15);
    int k0 = kb * 32 + (l >> 4) * 8;
    const float* W = wc + (size_t)i * HID * HID;
    bf16x8 v;
    #pragma unroll
    for (int j = 0; j < 8; ++j) v[j] = (__bf16)W[(size_t)(k0 + j) * HID + col];
    wcsw[i * 2048 + lid] = v;
  } else if (id < 6144 + 32768) {
    int id2 = id - 6144;
    int layer = id2 >> 14, lid = id2 & 16383;
    int l = lid & 63, frag = lid >> 6;
    int cb = frag & 31, kb = frag >> 5;
    int col = cb * 16 + (l & 15);
    int k0 = kb * 32 + (l >> 4) * 8;
    const float* wi = wih + (size_t)layer * 512 * HID;
    const float* wh = whh + (size_t)layer * 512 * HID;
    bf16x8 v;
    #pragma unroll
    for (int j = 0; j < 8; ++j) {
      int k = k0 + j;
      float val = (k < HID) ? wi[(size_t)col * HID + k] : wh[(size_t)col * HID + (k - HID)];
      v[j] = (__bf16)val;
    }
    wstk[layer * 16384 + lid] = v;
  }
}

// collapsed head: Wc[k] = sum_j lin1_w[k][j]*lin2_w[j]; b = lin1_b@lin2_w + lin2_b
__global__ void k_headprep(const float* __restrict__ l1w, const float* __restrict__ l1b,
                           const float* __restrict__ l2w, const float* __restrict__ l2b,
                           float* __restrict__ hw) {
  int k = threadIdx.x;
  if (k < HID + TT) {
    float s = 0.f;
    for (int j = 0; j < HID; ++j) s += l1w[(size_t)k * HID + j] * l2w[j];
    hw[k] = s;
  } else if (k == HID + TT) {
    float s = l2b[0];
    for (int j = 0; j < HID; ++j) s += l1b[j] * l2w[j];
    hw[HID + TT] = s;
  }
}

// ---------------- MFMA transform, 3 timesteps (bf16 cat in, fp8 cat out) ----------------

__global__ __launch_bounds__(256) void k_trans3(const u16* __restrict__ Xin,
    const float* __restrict__ aff, const bf16x8* __restrict__ wsw,
    u8* __restrict__ Y, int nblk, int N_) {
  int w = threadIdx.x >> 6, l = threadIdx.x & 63;
  int lr = l & 15, lk = l >> 4;
  int t = blockIdx.x / nblk;
  int blk = blockIdx.x - t * nblk;
  int rbase = blk * 64 + w * 16;
  int arow = rbase + lr;
  bool av = arow < N_;
  const float* fa = aff + t * 256;
  const float* fb = fa + 128;
  f32x4 acc[8];
  #pragma unroll
  for (int cb = 0; cb < 8; ++cb) acc[cb] = (f32x4){0.f, 0.f, 0.f, 0.f};
  #pragma unroll
  for (int kb = 0; kb < 4; ++kb) {
    int ko = kb * 32 + lk * 8;
    bf16x8 af;
    if (av) {
      uint4 u = *(const uint4*)(Xin + (size_t)arow * RS16 + t * 128 + ko);
      float4 a0 = *(const float4*)(fa + ko), a1 = *(const float4*)(fa + ko + 4);
      float4 b0 = *(const float4*)(fb + ko), b1 = *(const float4*)(fb + ko + 4);
      af[0] = (__bf16)(bf_lo(u.x) * a0.x + b0.x);
      af[1] = (__bf16)(bf_hi(u.x) * a0.y + b0.y);
      af[2] = (__bf16)(bf_lo(u.y) * a0.z + b0.z);
      af[3] = (__bf16)(bf_hi(u.y) * a0.w + b0.w);
      af[4] = (__bf16)(bf_lo(u.z) * a1.x + b1.x);
      af[5] = (__bf16)(bf_hi(u.z) * a1.y + b1.y);
      af[6] = (__bf16)(bf_lo(u.w) * a1.z + b1.z);
      af[7] = (__bf16)(bf_hi(u.w) * a1.w + b1.w);
    } else {
      #pragma unroll
      for (int j = 0; j < 8; ++j) af[j] = (__bf16)0.f;
    }
    #pragma unroll
    for (int cb = 0; cb < 8; ++cb) {
      bf16x8 bf = wsw[(kb * 8 + cb) * 64 + l];
      acc[cb] = mfma_bf16(af, bf, acc[cb]);
    }
  }
  #pragma unroll
  for (int cb = 0; cb < 8; ++cb)
    #pragma unroll
    for (int i2 = 0; i2 < 4; ++i2) {
      int orow = rbase + lk * 4 + i2;
      if (orow < N_)
        Y[(size_t)orow * RS8 + t * 128 + cb * 16 + lr] = f_to_fp8(acc[cb][i2]);
    }
}

// ---------------- 3-timestep aggregation (pull, fp8 in, bf16 out) ----------------

__global__ __launch_bounds__(256) void k_agg3(const u8* __restrict__ H8,
    const int* __restrict__ rowptr, const int2* __restrict__ csr,
    const float* __restrict__ selfn, const float* __restrict__ bias,
    u16* __restrict__ outp, int N_) {
  int wv = threadIdx.x >> 6, l = threadIdx.x & 63;
  int wid = blockIdx.x * 4 + wv, nw = gridDim.x * 4;
  float b0 = bias[2 * l], b1 = bias[2 * l + 1];
  u32* O32 = (u32*)outp;
  for (int n = wid; n < N_; n += nw) {
    const u16* self = (const u16*)(H8 + (size_t)n * RS8) + l;
    float sn = selfn[n];
    u16 u0 = self[0], u1 = self[64], u2 = self[128];
    float a00 = sn * fp8_to_f((u8)u0), a01 = sn * fp8_to_f((u8)(u0 >> 8));
    float a10 = sn * fp8_to_f((u8)u1), a11 = sn * fp8_to_f((u8)(u1 >> 8));
    float a20 = sn * fp8_to_f((u8)u2), a21 = sn * fp8_to_f((u8)(u2 >> 8));
    int e0 = rowptr[n], e1 = rowptr[n + 1];
    int e = e0;
    for (; e + 3 < e1; e += 4) {
      int2 c0 = csr[e], c1 = csr[e+1], c2 = csr[e+2], c3 = csr[e+3];
      const u16* p0 = (const u16*)(H8 + (size_t)c0.x * RS8) + l;
      const u16* p1 = (const u16*)(H8 + (size_t)c1.x * RS8) + l;
      const u16* p2 = (const u16*)(H8 + (size_t)c2.x * RS8) + l;
      const u16* p3 = (const u16*)(H8 + (size_t)c3.x * RS8) + l;
      u16 x00 = p0[0], x01 = p0[64], x02 = p0[128];
      u16 x10 = p1[0], x11 = p1[64], x12 = p1[128];
      u16 x20 = p2[0], x21 = p2[64], x22 = p2[128];
      u16 x30 = p3[0], x31 = p3[64], x32 = p3[128];
      float w0 = __int_as_float(c0.y), w1v = __int_as_float(c1.y);
      float w2 = __int_as_float(c2.y), w3v = __int_as_float(c3.y);
      a00 += w0 * fp8_to_f((u8)x00) + w1v * fp8_to_f((u8)x10)
           + w2 * fp8_to_f((u8)x20) + w3v * fp8_to_f((u8)x30);
      a01 += w0 * fp8_to_f((u8)(x00 >> 8)) + w1v * fp8_to_f((u8)(x10 >> 8))
           + w2 * fp8_to_f((u8)(x20 >> 8)) + w3v * fp8_to_f((u8)(x30 >> 8));
      a10 += w0 * fp8_to_f((u8)x01) + w1v * fp8_to_f((u8)x11)
           + w2 * fp8_to_f((u8)x21) + w3v * fp8_to_f((u8)x31);
      a11 += w0 * fp8_to_f((u8)(x01 >> 8)) + w1v * fp8_to_f((u8)(x11 >> 8))
           + w2 * fp8_to_f((u8)(x21 >> 8)) + w3v * fp8_to_f((u8)(x31 >> 8));
      a20 += w0 * fp8_to_f((u8)x02) + w1v * fp8_to_f((u8)x12)
           + w2 * fp8_to_f((u8)x22) + w3v * fp8_to_f((u8)x32);
      a21 += w0 * fp8_to_f((u8)(x02 >> 8)) + w1v * fp8_to_f((u8)(x12 >> 8))
           + w2 * fp8_to_f((u8)(x22 >> 8)) + w3v * fp8_to_f((u8)(x32 >> 8));
    }
    for (; e < e1; ++e) {
      int2 c0 = csr[e];
      const u16* p0 = (const u16*)(H8 + (size_t)c0.x * RS8) + l;
      u16 x00 = p0[0], x01 = p0[64], x02 = p0[128];
      float w0 = __int_as_float(c0.y);
      a00 += w0 * fp8_to_f((u8)x00); a01 += w0 * fp8_to_f((u8)(x00 >> 8));
      a10 += w0 * fp8_to_f((u8)x01); a11 += w0 * fp8_to_f((u8)(x01 >> 8));
      a20 += w0 * fp8_to_f((u8)x02); a21 += w0 * fp8_to_f((u8)(x02 >> 8));
    }
    u32* orow = O32 + (size_t)n * RS32 + l;
    orow[0]   = (u32)bfbits(fmaxf(a00 + b0, 0.f)) | ((u32)bfbits(fmaxf(a01 + b1, 0.f)) << 16);
    orow[64]  = (u32)bfbits(fmaxf(a10 + b0, 0.f)) | ((u32)bfbits(fmaxf(a11 + b1, 0.f)) << 16);
    orow[128] = (u32)bfbits(fmaxf(a20 + b0, 0.f)) | ((u32)bfbits(fmaxf(a21 + b1, 0.f)) << 16);
  }
}

// ---------------- fused LSTM step (bf16 x/h, fp32 c); x has stride xs ----------------

__global__ __launch_bounds__(256) void k_lstm(
    const u16* __restrict__ xb, int xs, const u16* __restrict__ hpb,
    const float* __restrict__ aff,   // [a(128) | b(128)] or nullptr
    float* __restrict__ cstate, u16* __restrict__ hout,
    const bf16x8* __restrict__ wsw, const float* __restrict__ bias,
    int first, int N_) {
  __shared__ __bf16 gl[32][512];   // 32 KiB
  int w = threadIdx.x >> 6, l = threadIdx.x & 63;
  int lr = l & 15, lk = l >> 4;
  int r0 = blockIdx.x * 32;
  f32x4 acc[2][8];
  #pragma unroll
  for (int rb = 0; rb < 2; ++rb)
    #pragma unroll
    for (int cb = 0; cb < 8; ++cb) acc[rb][cb] = (f32x4){0.f, 0.f, 0.f, 0.f};

  #pragma unroll
  for (int kb = 0; kb < 4; ++kb) {
    int ko = kb * 32 + lk * 8;
    bf16x8 af[2];
    #pragma unroll
    for (int rb = 0; rb < 2; ++rb) {
      int row = r0 + rb * 16 + lr;
      if (row < N_) {
        uint4 u = *(const uint4*)(xb + (size_t)row * xs + ko);
        if (aff) {
          float4 a0 = *(const float4*)(aff + ko),       a1 = *(const float4*)(aff + ko + 4);
          float4 b0 = *(const float4*)(aff + HID + ko), b1 = *(const float4*)(aff + HID + ko + 4);
          af[rb][0] = (__bf16)(bf_lo(u.x) * a0.x + b0.x);
          af[rb][1] = (__bf16)(bf_hi(u.x) * a0.y + b0.y);
          af[rb][2] = (__bf16)(bf_lo(u.y) * a0.z + b0.z);
          af[rb][3] = (__bf16)(bf_hi(u.y) * a0.w + b0.w);
          af[rb][4] = (__bf16)(bf_lo(u.z) * a1.x + b1.x);
          af[rb][5] = (__bf16)(bf_hi(u.z) * a1.y + b1.y);
          af[rb][6] = (__bf16)(bf_lo(u.w) * a1.z + b1.z);
          af[rb][7] = (__bf16)(bf_hi(u.w) * a1.w + b1.w);
        } else {
          af[rb] = __builtin_bit_cast(bf16x8, u);
        }
      } else {
        #pragma unroll
        for (int j = 0; j < 8; ++j) af[rb][j] = (__bf16)0.f;
      }
    }
    #pragma unroll
    for (int cb = 0; cb < 8; ++cb) {
      bf16x8 bf = wsw[(kb * 32 + w * 8 + cb) * 64 + l];
      acc[0][cb] = mfma_bf16(af[0], bf, acc[0][cb]);
      acc[1][cb] = mfma_bf16(af[1], bf, acc[1][cb]);
    }
  }
  if (!first) {
    #pragma unroll
    for (int kb = 0; kb < 4; ++kb) {
      int ko = kb * 32 + lk * 8;
      bf16x8 af[2];
      #pragma unroll
      for (int rb = 0; rb < 2; ++rb) {
        int row = r0 + rb * 16 + lr;
        if (row < N_) {
          af[rb] = __builtin_bit_cast(bf16x8, *(const uint4*)(hpb + (size_t)row * HID + ko));
        } else {
          #pragma unroll
          for (int j = 0; j < 8; ++j) af[rb][j] = (__bf16)0.f;
        }
      }
      #pragma unroll
      for (int cb = 0; cb < 8; ++cb) {
        bf16x8 bf = wsw[((kb + 4) * 32 + w * 8 + cb) * 64 + l];
        acc[0][cb] = mfma_bf16(af[0], bf, acc[0][cb]);
        acc[1][cb] = mfma_bf16(af[1], bf, acc[1][cb]);
      }
    }
  }
  #pragma unroll
  for (int rb = 0; rb < 2; ++rb)
    #pragma unroll
    for (int cb = 0; cb < 8; ++cb)
      #pragma unroll
      for (int i2 = 0; i2 < 4; ++i2)
        gl[rb * 16 + lk * 4 + i2][w * 128 + cb * 16 + lr] = (__bf16)acc[rb][cb][i2];
  __syncthreads();
  for (int it = threadIdx.x; it < 32 * HID; it += 256) {
    int nl = it >> 7, j = it & 127;
    int n = r0 + nl;
    if (n >= N_) continue;
    float ig = (float)gl[nl][j]       + bias[j];
    float fg = (float)gl[nl][128 + j] + bias[128 + j];
    float gg = (float)gl[nl][256 + j] + bias[256 + j];
    float og = (float)gl[nl][384 + j] + bias[384 + j];
    float cp = first ? 0.f : cstate[(size_t)n * HID + j];
    float cn = sigf(fg) * cp + sigf(ig) * tanhf(gg);
    float hn = sigf(og) * tanhf(cn);
    cstate[(size_t)n * HID + j] = cn;
    hout[(size_t)n * HID + j] = bfbits(hn);
  }
}

// ---------------- final head: out[n] = relu(h2[n]) . Wc + S . Ws + b ----------------

__global__ __launch_bounds__(256) void k_final2(const u32* __restrict__ H2,
    const float* __restrict__ Xin, const float* __restrict__ hw,
    float* __restrict__ outp, int N_) {
  int wv = threadIdx.x >> 6, l = threadIdx.x & 63;
  int wid = blockIdx.x * 4 + wv, nw = gridDim.x * 4;
  float wc0 = hw[2 * l], wc1 = hw[2 * l + 1];
  float ws0 = hw[HID], ws1 = hw[HID + 1], ws2 = hw[HID + 2], bb = hw[HID + 3];
  for (int n = wid; n < N_; n += nw) {
    u32 u = H2[(size_t)n * 64 + l];
    float p = fmaxf(bf_lo(u), 0.f) * wc0 + fmaxf(bf_hi(u), 0.f) * wc1;
    #pragma unroll
    for (int off = 32; off; off >>= 1) p += __shfl_down(p, off);
    if (l == 0) {
      p += Xin[(size_t)n * FIN] * ws0
         + Xin[((size_t)N_ + n) * FIN] * ws1
         + Xin[((size_t)2 * N_ + n) * FIN] * ws2;
      outp[n] = p + bb;
    }
  }
}

// ---------------- host ----------------

extern "C" void kernel_launch(void* const* d_in, const int* in_sizes, int n_in,
                              void* d_out, int out_size, void* d_ws, size_t ws_size,
                              hipStream_t stream) {
  const float* X   = (const float*)d_in[0];
  const int*   ei  = (const int*)  d_in[1];
  const float* ew  = (const float*)d_in[2];
  const float* w1  = (const float*)d_in[3];
  const float* wc  = (const float*)d_in[4];
  const float* bc  = (const float*)d_in[5];
  const float* gam = (const float*)d_in[6];
  const float* bet = (const float*)d_in[7];
  const float* wih = (const float*)d_in[8];
  const float* whh = (const float*)d_in[9];
  const float* lb  = (const float*)d_in[10];
  const float* l1w = (const float*)d_in[11];
  const float* l1b = (const float*)d_in[12];
  const float* l2w = (const float*)d_in[13];
  const float* l2b = (const float*)d_in[14];
  float* outp = (float*)d_out;
  (void)n_in; (void)out_size; (void)ws_size;

  const int N = in_sizes[0] / (TT * FIN);
  const int E = in_sizes[1] / 2;
  const int* srcv = ei;
  const int* dstv = ei + E;

  char* base = (char*)d_ws;
  size_t off = 0;
  auto alloc = [&](size_t b) -> void* {
    void* p = base + off;
    off += (b + 255) & ~(size_t)255;
    return p;
  };

  u64*   pk     = (u64*)  alloc((size_t)N * 8);
  int*   epos   = (int*)  alloc((size_t)E * 4);
  int*   rowptr = (int*)  alloc(((size_t)N + 1) * 4);
  int*   partial= (int*)  alloc(1024);
  float* dinv   = (float*)alloc((size_t)N * 4);
  float* selfn  = (float*)alloc((size_t)N * 4);
  int2*  csr    = (int2*) alloc((size_t)E * 8);
  float* XA     = (float*)alloc((size_t)N * 12 * 4);
  u16*   Ga     = (u16*)  alloc((size_t)N * RS16 * 2);   // cat bf16 layouts
  u16*   Gb     = (u16*)  alloc((size_t)N * RS16 * 2);
  u8*    Htb    = (u8*)   alloc((size_t)N * RS8);        // fp8 gather table
  u16*   Gcat   = (u16*)  alloc((size_t)N * RS16 * 2);
  float* stats  = (float*)alloc(768 * 4);
  int*   ticket = (int*)  alloc(256);
  float* affA   = (float*)alloc((size_t)3 * 256 * 4);
  float* aff3   = (float*)alloc((size_t)3 * 256 * 4);
  float* hw     = (float*)alloc(136 * 4);
  bf16x8* wcsw  = (bf16x8*)alloc((size_t)3 * 2048 * 16);
  bf16x8* wstk  = (bf16x8*)alloc((size_t)2 * 16384 * 16);
  // aliases: GCN ping-pong buffers are dead once LSTM starts
  u16*   Cb     = Ga;                    // 3*N*128*2 = N*RS16*2 bytes exactly
  float* cbuf   = (float*)Gb;            // N*128*4 <= N*RS16*2

  int gN = (N + 255) / 256, gE = (E + 255) / 256;
  int nb = (N + 255) / 256;
  int nblk = (N + 63) / 64;

  k_init<<<gN, 256, 0, stream>>>(pk, stats, ticket, N);
  k_deg<<<gE, 256, 0, stream>>>(dstv, ew, pk, epos, E);
  k_scanA<<<nb, 256, 0, stream>>>(pk, rowptr, partial, dinv, selfn, N);
  k_scanB<<<1, 256, 0, stream>>>(partial, nb);
  k_scanC<<<nb, 256, 0, stream>>>(rowptr, partial, N);
  k_fillcsr<<<gE, 256, 0, stream>>>(srcv, dstv, ew, dinv, rowptr, epos, csr, E);
  k_aggX<<<1024, 256, 0, stream>>>(X, rowptr, csr, selfn, XA, N);
  k_swzall<<<152, 256, 0, stream>>>(wc, wih, whh, wcsw, wstk);
  k_headprep<<<1, 256, 0, stream>>>(l1w, l1b, l2w, l2b, hw);

  // GCN chain, all 3 timesteps per launch; gather operand in fp8
  k_l0c<<<(N * 64 + 255) / 256, 256, 0, stream>>>(XA, w1, bc, (u32*)Ga, N);
  k_stats3<<<256, 256, 0, stream>>>((const u32*)Ga, stats, ticket, gam, bet, affA, N);

  k_trans3<<<3 * nblk, 256, 0, stream>>>(Ga, affA, wcsw, Htb, nblk, N);
  k_agg3<<<2048, 256, 0, stream>>>(Htb, rowptr, csr, selfn, bc + HID, Gb, N);
  k_stats3<<<256, 256, 0, stream>>>((const u32*)Gb, stats, ticket, gam + HID, bet + HID, affA, N);

  k_trans3<<<3 * nblk, 256, 0, stream>>>(Gb, affA, wcsw + 2048, Htb, nblk, N);
  k_agg3<<<2048, 256, 0, stream>>>(Htb, rowptr, csr, selfn, bc + 2 * HID, Gb, N);
  k_stats3<<<256, 256, 0, stream>>>((const u32*)Gb, stats, ticket, gam + 2 * HID, bet + 2 * HID, affA, N);

  k_trans3<<<3 * nblk, 256, 0, stream>>>(Gb, affA, wcsw + 4096, Htb, nblk, N);
  k_agg3<<<2048, 256, 0, stream>>>(Htb, rowptr, csr, selfn, bc + 3 * HID, Gcat, N);
  k_stats3<<<256, 256, 0, stream>>>((const u32*)Gcat, stats, ticket, gam + 3 * HID, bet + 3 * HID, aff3, N);

  // LSTM (Cb aliases Ga, cbuf aliases Gb — both GCN buffers dead now)
  int gL = (N + 31) / 32;
  for (int t = 0; t < TT; ++t) {
    u16* Ct = Cb + (size_t)t * N * HID;
    const u16* hp = (t == 0) ? Ct : (Cb + (size_t)(t - 1) * N * HID);
    k_lstm<<<gL, 256, 0, stream>>>(Gcat + (size_t)t * HID, RS16, hp,
                                   aff3 + (size_t)t * 256, cbuf, Ct,
                                   wstk, lb, (t == 0) ? 1 : 0, N);
  }
  for (int t = 0; t < TT; ++t) {
    u16* Ct = Cb + (size_t)t * N * HID;
    const u16* hp = (t == 0) ? Ct : (Cb + (size_t)(t - 1) * N * HID);
    k_lstm<<<gL, 256, 0, stream>>>(Ct, HID, hp, nullptr, cbuf, Ct,
                                   wstk + 16384, lb + 512, (t == 0) ? 1 : 0, N);
  }
  k_final2<<<512, 256, 0, stream>>>((const u32*)(Cb + (size_t)2 * N * HID), X, hw, outp, N);
}